// Round 10
// baseline (271.608 us; speedup 1.0000x reference)
//
#include <hip/hip_runtime.h>
#include <math.h>

#define BB   32
#define CC   512
#define HWW  1024
#define OUTC 256
#define EPSV 1e-5f

typedef __attribute__((ext_vector_type(8))) short bfrag;
typedef __attribute__((ext_vector_type(4))) float f32x4;
typedef __attribute__((ext_vector_type(4))) unsigned int u32x4;

__device__ inline unsigned short f2bf(float x){
  unsigned int uu = __float_as_uint(x);
  uu += 0x7fff + ((uu >> 16) & 1);      // round-to-nearest-even
  return (unsigned short)(uu >> 16);
}
__device__ inline float bf2f(unsigned short h){
  return __uint_as_float(((unsigned int)h) << 16);
}
// pack two floats -> (bf16 hi pair, bf16 lo-residual pair) words
__device__ inline void packpair(float v0, float v1, unsigned int& hw, unsigned int& lw){
  unsigned short h0 = f2bf(v0), h1 = f2bf(v1);
  unsigned short l0 = f2bf(v0 - bf2f(h0)), l1 = f2bf(v1 - bf2f(h1));
  hw = (unsigned int)h0 | ((unsigned int)h1 << 16);
  lw = (unsigned int)l0 | ((unsigned int)l1 << 16);
}

// ===========================================================================
// MAIN PATH (split-bf16 MFMA, 3 dispatches, fragment-linear layouts)
// ===========================================================================
// Fragment-linear layout: matrix [rows][K] stored as tiles of 16 rows x 32 k.
// Tile (R = row>>4, Kq = k>>5) occupies 512 contiguous shorts; lane
// l = ((k>>3)&3)*16 + (row&15) holds shorts [l*8, l*8+8) (k&7 fastest).
// A wave's MFMA fragment load is ONE coalesced 1KB global_load_dwordx4.
//
// R10: g1 wave tile 64x64 -> 64x32 (block 128x64, acc[4][2]=32 AGPR) while
// KEEPING the R8 register double-buffer. ~145 unified regs -> 3 waves/SIMD
// (launch_bounds(256,3)). R8 showed dbuf at 2 waves/SIMD = MfmaUtil 33;
// R5 showed 3 waves no-dbuf = 30. Latency cover = dbuf-depth x waves/SIMD;
// this gets both. k4 reverted to R8 form (R9's 4-row batch was neutral).

// --- prep: weight-convert + accumulator zeroing (z==32) + x hi/lo + transpose
__global__ __launch_bounds__(256) void prep(
    const float* __restrict__ x,
    const float* __restrict__ w1, const float* __restrict__ w2,
    const float* __restrict__ w3,
    unsigned short* __restrict__ Xhi, unsigned short* __restrict__ Xlo,
    unsigned short* __restrict__ XThi,
    unsigned short* __restrict__ Whi, unsigned short* __restrict__ Wlo,
    unsigned short* __restrict__ W3hi,
    float* __restrict__ accz)          // xe_acc|u|t contiguous, 32768 floats
{
  const int tid = threadIdx.x;
  if (blockIdx.z == 32) {
    int worker = (blockIdx.y * 16 + blockIdx.x) * 256 + tid;  // < 32768
    accz[worker] = 0.f;                 // replaces hipMemsetAsync dispatch
    // W1|W2 -> Whi/Wlo fragment-linear: 1024 tiles x 64 chunks, 2 per worker.
#pragma unroll
    for (int s = 0; s < 2; ++s) {
      int cid  = worker * 2 + s;
      int tile = cid >> 6, l = cid & 63;
      int o = (tile >> 5) * 16 + (l & 15);
      int k = (tile & 31) * 32 + (l >> 4) * 8;
      const float* src = (o < 256) ? (w1 + (size_t)o * 1024 + k)
                                   : (w2 + (size_t)(o - 256) * 1024 + k);
      u32x4 hv, lv;
#pragma unroll
      for (int j = 0; j < 4; ++j) {
        unsigned int hw, lw;
        packpair(src[2 * j], src[2 * j + 1], hw, lw);
        hv[j] = hw; lv[j] = lw;
      }
      size_t base = (size_t)tile * 512 + (size_t)l * 8;
      *(u32x4*)(Whi + base) = hv;
      *(u32x4*)(Wlo + base) = lv;
    }
    // W3 -> W3hi fragment-linear: 512 tiles x 64 chunks, 1 per worker.
    {
      int tile = worker >> 6, l = worker & 63;
      int o = (tile >> 4) * 16 + (l & 15);
      int c = (tile & 15) * 32 + (l >> 4) * 8;
      const float* src = w3 + (size_t)o * 512 + c;
      u32x4 hv;
#pragma unroll
      for (int j = 0; j < 4; ++j) {
        unsigned short h0 = f2bf(src[2 * j]), h1 = f2bf(src[2 * j + 1]);
        hv[j] = (unsigned int)h0 | ((unsigned int)h1 << 16);
      }
      *(u32x4*)(W3hi + (size_t)tile * 512 + (size_t)l * 8) = hv;
    }
    return;
  }
  // ---- x hi/lo + transpose: one 64c x 64p tile per block, all via LDS ----
  __shared__ float T[64][65];
  const int b = blockIdx.z, c0 = blockIdx.y * 64, p0 = blockIdx.x * 64;
  const int tr = tid >> 4, tc4 = (tid & 15) * 4;
  const float* xb = x + (size_t)b * 524288;
#pragma unroll
  for (int r = 0; r < 4; ++r) {
    int cl = tr + r * 16;
    float4 v = *(const float4*)(xb + (size_t)(c0 + cl) * 1024 + p0 + tc4);
    T[cl][tc4 + 0] = v.x; T[cl][tc4 + 1] = v.y;
    T[cl][tc4 + 2] = v.z; T[cl][tc4 + 3] = v.w;
  }
  __syncthreads();
  // Xhi/Xlo: 8 frag tiles (4 cT x 2 pT), 512 chunks, 2 per thread.
#pragma unroll
  for (int s = 0; s < 2; ++s) {
    int cid  = tid + s * 256;
    int tile = cid >> 6, l = cid & 63;
    int tileC = tile >> 1, tileP = tile & 1;
    int cl = tileC * 16 + (l & 15);
    int pl = tileP * 32 + (l >> 4) * 8;
    u32x4 hv, lv;
#pragma unroll
    for (int j = 0; j < 4; ++j) {
      unsigned int hw, lw;
      packpair(T[cl][pl + 2 * j], T[cl][pl + 2 * j + 1], hw, lw);
      hv[j] = hw; lv[j] = lw;
    }
    size_t base = (size_t)b * 524288
                + ((size_t)((c0 + cl) >> 4) * 32 + (size_t)((p0 + pl) >> 5)) * 512
                + (size_t)l * 8;
    *(u32x4*)(Xhi + base) = hv;
    *(u32x4*)(Xlo + base) = lv;
  }
  // XThi: 8 frag tiles (4 pT x 2 cT), 512 chunks, 2 per thread.
#pragma unroll
  for (int s = 0; s < 2; ++s) {
    int cid  = tid + s * 256;
    int tile = cid >> 6, l = cid & 63;
    int tileP = tile >> 1, tileC = tile & 1;
    int pl = tileP * 16 + (l & 15);
    int cl = tileC * 32 + (l >> 4) * 8;
    u32x4 hv;
#pragma unroll
    for (int j = 0; j < 4; ++j) {
      unsigned short h0 = f2bf(T[cl + 2 * j][pl]);
      unsigned short h1 = f2bf(T[cl + 2 * j + 1][pl]);
      hv[j] = (unsigned int)h0 | ((unsigned int)h1 << 16);
    }
    size_t base = (size_t)b * 524288
                + ((size_t)((p0 + pl) >> 4) * 16 + (size_t)((c0 + cl) >> 5)) * 512
                + (size_t)l * 8;
    *(u32x4*)(XThi + base) = hv;
  }
}

// fragment-set helpers (arrays fully unrolled -> registers; rule #20 safe)
__device__ __forceinline__ void g1_load(
    const bfrag* Ah, const bfrag* Al, const bfrag* Bh, const bfrag* Bl,
    int kq, bfrag ah[4], bfrag al[4], bfrag bh[2], bfrag bl[2])
{
#pragma unroll
  for (int j = 0; j < 2; ++j) {
    bh[j] = Bh[(size_t)j * 2048 + kq * 64];
    bl[j] = Bl[(size_t)j * 2048 + kq * 64];
  }
#pragma unroll
  for (int i = 0; i < 4; ++i) {
    ah[i] = Ah[(size_t)i * 2048 + kq * 64];
    al[i] = Al[(size_t)i * 2048 + kq * 64];
  }
  __builtin_amdgcn_sched_barrier(0);   // pin load burst before following MFMAs
}
__device__ __forceinline__ void g1_mfma(
    f32x4 acc[4][2], const bfrag ah[4], const bfrag al[4],
    const bfrag bh[2], const bfrag bl[2])
{
#pragma unroll
  for (int i = 0; i < 4; ++i)
#pragma unroll
    for (int j = 0; j < 2; ++j) {
      acc[i][j] = __builtin_amdgcn_mfma_f32_16x16x32_bf16(ah[i], bh[j], acc[i][j], 0, 0, 0);
      acc[i][j] = __builtin_amdgcn_mfma_f32_16x16x32_bf16(ah[i], bl[j], acc[i][j], 0, 0, 0);
      acc[i][j] = __builtin_amdgcn_mfma_f32_16x16x32_bf16(al[i], bh[j], acc[i][j], 0, 0, 0);
    }
}
__device__ __forceinline__ void g2_load(
    const bfrag* Af, const bfrag* Bf, int kq, bfrag af[4], bfrag bf4[4])
{
#pragma unroll
  for (int i = 0; i < 4; ++i) af[i] = Af[(size_t)i * 1024 + kq * 64];
#pragma unroll
  for (int j = 0; j < 4; ++j) bf4[j] = Bf[(size_t)j * 1024 + kq * 64];
  __builtin_amdgcn_sched_barrier(0);
}
__device__ __forceinline__ void g2_mfma(
    f32x4 acc[4][4], const bfrag af[4], const bfrag bf4[4])
{
#pragma unroll
  for (int i = 0; i < 4; ++i)
#pragma unroll
    for (int j = 0; j < 4; ++j)
      acc[i][j] = __builtin_amdgcn_mfma_f32_16x16x32_bf16(af[i], bf4[j], acc[i][j], 0, 0, 0);
}

// --- gemm_fused: ids [0,1024) = g1 (128c x 64oo tiles, split-bf16, K=1024)
//                 ids [1024,2048) = g2 (128o x 128p tiles, bf16, K=512)
// Barrier-free / LDS-free; fragment-linear operands; register double-buffer
// at 3 waves/SIMD.
__global__ __launch_bounds__(256, 3) void gemm_fused(
    const unsigned short* __restrict__ Xhi, const unsigned short* __restrict__ Xlo,
    const unsigned short* __restrict__ Whi, const unsigned short* __restrict__ Wlo,
    const unsigned short* __restrict__ W3hi, const unsigned short* __restrict__ XThi,
    const float* __restrict__ b1p, const float* __restrict__ g1p,
    const float* __restrict__ be1p, const float* __restrict__ m1p, const float* __restrict__ v1p,
    const float* __restrict__ b2p, const float* __restrict__ g2p,
    const float* __restrict__ be2p, const float* __restrict__ m2p, const float* __restrict__ v2p,
    const float* __restrict__ b3p, const float* __restrict__ g3p,
    const float* __restrict__ be3p, const float* __restrict__ m3p, const float* __restrict__ v3p,
    const float* __restrict__ w4,
    float* __restrict__ P2, float* __restrict__ u, float* __restrict__ t,
    float* __restrict__ xe_acc)
{
  const int fid  = blockIdx.x;
  const int tid  = threadIdx.x;
  const int wave = tid >> 6, lane = tid & 63;
  const int fr = lane & 15, fq = lane >> 4;

  if (fid < 1024) {
    // ================= g1: P2[b][c][oo] =================
    // XCD decode: the 8 n-tiles of one X-panel (same b,c0) -> same XCD.
    const int xcd = fid & 7;
    const int n0  = ((fid >> 3) & 7) * 64;            // oo tile (64-wide)
    const int bc  = ((fid >> 6) << 3) | xcd;          // 0..127
    const int b   = bc >> 2;
    const int c0  = (bc & 3) * 128;
    const int wm = wave & 1, wn = wave >> 1;          // 64x32 per wave

    const bfrag* Ah = (const bfrag*)Xhi + (size_t)b * 65536
                    + (size_t)((c0 >> 4) + wm * 4) * 2048 + lane;
    const bfrag* Al = (const bfrag*)Xlo + (size_t)b * 65536
                    + (size_t)((c0 >> 4) + wm * 4) * 2048 + lane;
    const bfrag* Bh = (const bfrag*)Whi + (size_t)((n0 >> 4) + wn * 2) * 2048 + lane;
    const bfrag* Bl = (const bfrag*)Wlo + (size_t)((n0 >> 4) + wn * 2) * 2048 + lane;

    f32x4 acc[4][2];
    const f32x4 zz = {0.f, 0.f, 0.f, 0.f};
#pragma unroll
    for (int i = 0; i < 4; ++i) { acc[i][0] = zz; acc[i][1] = zz; }

    bfrag ahA[4], alA[4], bhA[2], blA[2];
    bfrag ahB[4], alB[4], bhB[2], blB[2];
    g1_load(Ah, Al, Bh, Bl, 0, ahA, alA, bhA, blA);
    for (int kq = 0; kq < 32; kq += 2) {
      g1_load(Ah, Al, Bh, Bl, kq + 1, ahB, alB, bhB, blB);
      g1_mfma(acc, ahA, alA, bhA, blA);
      if (kq + 2 < 32)
        g1_load(Ah, Al, Bh, Bl, kq + 2, ahA, alA, bhA, blA);
      g1_mfma(acc, ahB, alB, bhB, blB);
    }

    const float *bias, *gg, *bes, *mm, *vv_; int cof;
    if (n0 < 256) { bias = b1p; gg = g1p; bes = be1p; mm = m1p; vv_ = v1p; cof = 0; }
    else          { bias = b2p; gg = g2p; bes = be2p; mm = m2p; vv_ = v2p; cof = 256; }
    const float* wsel = (n0 < 256) ? (w4 + 513) : (w4 + 1);   // theta->t, phi->u
    float* dsel = (n0 < 256) ? (t + b * 256) : (u + b * 256);
    const int cobase = (n0 - cof) + wn * 32;
    float wt[4][4];
#pragma unroll
    for (int i = 0; i < 4; ++i)
#pragma unroll
      for (int r = 0; r < 4; ++r)
        wt[i][r] = wsel[c0 + wm * 64 + i * 16 + fq * 4 + r];

#pragma unroll
    for (int j = 0; j < 2; ++j) {
      int co = n0 + wn * 32 + j * 16 + fr;
      int q = co - cof;
      float s  = gg[q] * rsqrtf(vv_[q] + EPSV);
      float sh = (bias[q] - mm[q]) * s + bes[q];
      float psum = 0.f;
#pragma unroll
      for (int i = 0; i < 4; ++i) {
        int crow = c0 + wm * 64 + i * 16 + fq * 4;
        float* dst = P2 + ((size_t)b * 512 + crow) * 512 + co;
#pragma unroll
        for (int r = 0; r < 4; ++r) {
          float val = fmaxf(acc[i][j][r] * s + sh, 0.f);
          dst[(size_t)r * 512] = val;
          psum += wt[i][r] * val;
        }
      }
      psum += __shfl_xor(psum, 16);
      psum += __shfl_xor(psum, 32);
      if (fq == 0) atomicAdd(&dsel[cobase + j * 16 + fr], psum);
    }
  } else {
    // ================= g2: xe_acc[b][o] =================
    const int h  = fid - 1024;
    const int n0 = (h & 7) * 128;                    // p tile
    const int m0 = ((h >> 3) & 3) * 128;             // o tile
    const int b  = h >> 5;
    const int wm = wave & 1, wn = wave >> 1;

    const bfrag* Af = (const bfrag*)W3hi + (size_t)((m0 >> 4) + wm * 4) * 1024 + lane;
    const bfrag* Bf = (const bfrag*)XThi + (size_t)b * 65536
                    + (size_t)((n0 >> 4) + wn * 4) * 1024 + lane;

    f32x4 acc[4][4];
    const f32x4 zz = {0.f, 0.f, 0.f, 0.f};
#pragma unroll
    for (int i = 0; i < 4; ++i)
#pragma unroll
      for (int j = 0; j < 4; ++j) acc[i][j] = zz;

    bfrag afA[4], bfA[4], afB[4], bfB[4];
    g2_load(Af, Bf, 0, afA, bfA);
    for (int kq = 0; kq < 16; kq += 2) {
      g2_load(Af, Bf, kq + 1, afB, bfB);
      g2_mfma(acc, afA, bfA);
      if (kq + 2 < 16)
        g2_load(Af, Bf, kq + 2, afA, bfA);
      g2_mfma(acc, afB, bfB);
    }

#pragma unroll
    for (int i = 0; i < 4; ++i) {
#pragma unroll
      for (int r = 0; r < 4; ++r) {
        int o = m0 + wm * 64 + i * 16 + fq * 4 + r;
        float s  = g3p[o] * rsqrtf(v3p[o] + EPSV);
        float sh = (b3p[o] - m3p[o]) * s + be3p[o];
        float v = fmaxf(acc[i][0][r] * s + sh, 0.f) + fmaxf(acc[i][1][r] * s + sh, 0.f)
                + fmaxf(acc[i][2][r] * s + sh, 0.f) + fmaxf(acc[i][3][r] * s + sh, 0.f);
        v += __shfl_xor(v, 1); v += __shfl_xor(v, 2);
        v += __shfl_xor(v, 4); v += __shfl_xor(v, 8);
        if (fr == 0) atomicAdd(&xe_acc[b * 512 + o], v);
      }
    }
  }
}

// --- k4: logits -> sigmoid -> gate multiply (one wave per (b,p)) ------------
__global__ __launch_bounds__(256) void k4_gate_out(
    const float* __restrict__ P2, const float* __restrict__ u,
    const float* __restrict__ t, const float* __restrict__ xe_acc,
    const float* __restrict__ w4, const float* __restrict__ b4,
    const float* __restrict__ x, float* __restrict__ out)
{
  __shared__ float us[256], ts[256];
  const int b = blockIdx.x;
  us[threadIdx.x] = u[b * 256 + threadIdx.x];
  ts[threadIdx.x] = t[b * 256 + threadIdx.x];
  __syncthreads();
  const int wave = threadIdx.x >> 6, lane = threadIdx.x & 63;
  const int p = blockIdx.y * 4 + wave;
  const float* row = P2 + ((size_t)b * 512 + p) * 512;
  float4 th = *(const float4*)&row[lane * 4];
  float4 ph = *(const float4*)&row[256 + lane * 4];
  int ki = lane * 4;
  float rs = th.x * us[ki] + th.y * us[ki + 1] + th.z * us[ki + 2] + th.w * us[ki + 3]
           + ph.x * ts[ki] + ph.y * ts[ki + 1] + ph.z * ts[ki + 2] + ph.w * ts[ki + 3];
  rs += __shfl_xor(rs, 1);  rs += __shfl_xor(rs, 2);  rs += __shfl_xor(rs, 4);
  rs += __shfl_xor(rs, 8);  rs += __shfl_xor(rs, 16); rs += __shfl_xor(rs, 32);
  float xe = xe_acc[b * 512 + p] * (1.f / 1024.f);
  float logit = w4[0] * xe + rs + b4[0];
  float a = 1.f / (1.f + expf(-logit));
  const float4* xr = (const float4*)(x + ((size_t)b * 512 + p) * 1024);
  float4* orow = (float4*)(out + ((size_t)b * 512 + p) * 1024);
#pragma unroll
  for (int r2 = 0; r2 < 4; ++r2) {
    float4 xv = xr[lane + r2 * 64];
    float4 ov; ov.x = xv.x * a; ov.y = xv.y * a; ov.z = xv.z * a; ov.w = xv.w * a;
    orow[lane + r2 * 64] = ov;
  }
}

// ===========================================================================
// FALLBACK PATH (round-1 fp32, used only if ws_size too small)
// ===========================================================================
__global__ __launch_bounds__(256) void k1_theta_phi(
    const float* __restrict__ x,
    const float* __restrict__ w1, const float* __restrict__ b1,
    const float* __restrict__ g1, const float* __restrict__ be1,
    const float* __restrict__ m1, const float* __restrict__ v1,
    const float* __restrict__ w2, const float* __restrict__ b2,
    const float* __restrict__ g2, const float* __restrict__ be2,
    const float* __restrict__ m2, const float* __restrict__ v2,
    float* __restrict__ P)
{
  __shared__ __align__(16) float Ws[32][68];
  __shared__ __align__(16) float Xs[32][68];
  const int b  = blockIdx.z;
  const int o0 = blockIdx.y * 64;
  const int c0 = blockIdx.x * 64;
  const int tid = threadIdx.x;
  const int tx = tid & 15, ty = tid >> 4;
  const float* __restrict__ Wbase = (o0 < OUTC) ? (w1 + (size_t)o0 * HWW)
                                                : (w2 + (size_t)(o0 - OUTC) * HWW);
  const float* __restrict__ xb = x + (size_t)b * CC * HWW;
  float acc[4][4] = {{0.f}};
  for (int k0 = 0; k0 < HWW; k0 += 32) {
#pragma unroll
    for (int r = 0; r < 2; ++r) {
      int id  = tid + (r << 8);
      int row = id >> 3;
      int cg  = (id & 7) << 2;
      float4 wv = *(const float4*)(Wbase + (size_t)row * HWW + k0 + cg);
      Ws[cg+0][row] = wv.x; Ws[cg+1][row] = wv.y; Ws[cg+2][row] = wv.z; Ws[cg+3][row] = wv.w;
      float4 xv = *(const float4*)(xb + (size_t)(c0 + row) * HWW + k0 + cg);
      Xs[cg+0][row] = xv.x; Xs[cg+1][row] = xv.y; Xs[cg+2][row] = xv.z; Xs[cg+3][row] = xv.w;
    }
    __syncthreads();
#pragma unroll
    for (int k = 0; k < 32; ++k) {
      float4 av = *(const float4*)&Ws[k][ty * 4];
      float4 bv = *(const float4*)&Xs[k][tx * 4];
      acc[0][0] += av.x*bv.x; acc[0][1] += av.x*bv.y; acc[0][2] += av.x*bv.z; acc[0][3] += av.x*bv.w;
      acc[1][0] += av.y*bv.x; acc[1][1] += av.y*bv.y; acc[1][2] += av.y*bv.z; acc[1][3] += av.y*bv.w;
      acc[2][0] += av.z*bv.x; acc[2][1] += av.z*bv.y; acc[2][2] += av.z*bv.z; acc[2][3] += av.z*bv.w;
      acc[3][0] += av.w*bv.x; acc[3][1] += av.w*bv.y; acc[3][2] += av.w*bv.z; acc[3][3] += av.w*bv.w;
    }
    __syncthreads();
  }
  const float *bias, *g, *be, *m, *v; int ob;
  if (o0 < OUTC) { bias = b1; g = g1; be = be1; m = m1; v = v1; ob = o0; }
  else           { bias = b2; g = g2; be = be2; m = m2; v = v2; ob = o0 - OUTC; }
#pragma unroll
  for (int i = 0; i < 4; ++i) {
    int oi = ob + ty * 4 + i;
    float sc = g[oi] * rsqrtf(v[oi] + EPSV);
    float sh = be[oi] - m[oi] * sc;
    float bb = bias[oi];
    float4 ov;
    ov.x = fmaxf((acc[i][0] + bb) * sc + sh, 0.f);
    ov.y = fmaxf((acc[i][1] + bb) * sc + sh, 0.f);
    ov.z = fmaxf((acc[i][2] + bb) * sc + sh, 0.f);
    ov.w = fmaxf((acc[i][3] + bb) * sc + sh, 0.f);
    int oo = o0 + ty * 4 + i;
    *(float4*)(P + ((size_t)b * 512 + oo) * 512 + c0 + tx * 4) = ov;
  }
}

__global__ __launch_bounds__(256) void k2_xe(
    const float* __restrict__ x, const float* __restrict__ w3,
    const float* __restrict__ b3, const float* __restrict__ g3,
    const float* __restrict__ be3, const float* __restrict__ m3,
    const float* __restrict__ v3, float* __restrict__ xe_acc)
{
  __shared__ __align__(16) float As[32][68];
  __shared__ __align__(16) float Bs[32][68];
  const int b  = blockIdx.z;
  const int o0 = blockIdx.y * 64;
  const int p0 = blockIdx.x * 64;
  const int tid = threadIdx.x;
  const int tx = tid & 15, ty = tid >> 4;
  const float* __restrict__ xb = x + (size_t)b * CC * HWW;
  float acc[4][4] = {{0.f}};
  for (int ck = 0; ck < CC; ck += 32) {
#pragma unroll
    for (int r = 0; r < 2; ++r) {
      int id  = tid + (r << 8);
      int row = id >> 3;
      int cg  = (id & 7) << 2;
      float4 wv = *(const float4*)(w3 + (size_t)(o0 + row) * CC + ck + cg);
      As[cg+0][row] = wv.x; As[cg+1][row] = wv.y; As[cg+2][row] = wv.z; As[cg+3][row] = wv.w;
      int brow = id >> 4;
      int pg   = (id & 15) << 2;
      float4 xv = *(const float4*)(xb + (size_t)(ck + brow) * HWW + p0 + pg);
      *(float4*)&Bs[brow][pg] = xv;
    }
    __syncthreads();
#pragma unroll
    for (int k = 0; k < 32; ++k) {
      float4 av = *(const float4*)&As[k][ty * 4];
      float4 bv = *(const float4*)&Bs[k][tx * 4];
      acc[0][0] += av.x*bv.x; acc[0][1] += av.x*bv.y; acc[0][2] += av.x*bv.z; acc[0][3] += av.x*bv.w;
      acc[1][0] += av.y*bv.x; acc[1][1] += av.y*bv.y; acc[1][2] += av.y*bv.z; acc[1][3] += av.y*bv.w;
      acc[2][0] += av.z*bv.x; acc[2][1] += av.z*bv.y; acc[2][2] += av.z*bv.z; acc[2][3] += av.z*bv.w;
      acc[3][0] += av.w*bv.x; acc[3][1] += av.w*bv.y; acc[3][2] += av.w*bv.z; acc[3][3] += av.w*bv.w;
    }
    __syncthreads();
  }
#pragma unroll
  for (int i = 0; i < 4; ++i) {
    int oo = o0 + ty * 4 + i;
    float sc = g3[oo] * rsqrtf(v3[oo] + EPSV);
    float sh = be3[oo] - m3[oo] * sc;
    float bb = b3[oo];
    float ps = fmaxf((acc[i][0] + bb) * sc + sh, 0.f)
             + fmaxf((acc[i][1] + bb) * sc + sh, 0.f)
             + fmaxf((acc[i][2] + bb) * sc + sh, 0.f)
             + fmaxf((acc[i][3] + bb) * sc + sh, 0.f);
    ps += __shfl_xor(ps, 1);
    ps += __shfl_xor(ps, 2);
    ps += __shfl_xor(ps, 4);
    ps += __shfl_xor(ps, 8);
    if (tx == 0) atomicAdd(&xe_acc[b * CC + oo], ps);
  }
}

__global__ __launch_bounds__(256) void k3_ut(
    const float* __restrict__ P, const float* __restrict__ w4,
    float* __restrict__ u, float* __restrict__ t)
{
  const int b = blockIdx.x;
  const int wv = threadIdx.x >> 6, lane = threadIdx.x & 63;
  const int k = blockIdx.y * 4 + wv;
  const float* __restrict__ w4a = w4 + 1;
  const float* __restrict__ w4b = w4 + 1 + CC;
  const float* __restrict__ throw_ = P + ((size_t)b * 512 + k) * 512;
  const float* __restrict__ phrow  = P + ((size_t)b * 512 + 256 + k) * 512;
  float su = 0.f, st = 0.f;
#pragma unroll
  for (int i = lane; i < CC; i += 64) {
    su += w4a[i] * phrow[i];
    st += w4b[i] * throw_[i];
  }
#pragma unroll
  for (int off = 32; off > 0; off >>= 1) {
    su += __shfl_down(su, off);
    st += __shfl_down(st, off);
  }
  if (lane == 0) { u[b * OUTC + k] = su; t[b * OUTC + k] = st; }
}

__global__ __launch_bounds__(256) void k4_gate(
    const float* __restrict__ P, const float* __restrict__ u,
    const float* __restrict__ t, const float* __restrict__ xe_acc,
    const float* __restrict__ w4, const float* __restrict__ b4,
    float* __restrict__ amul)
{
  __shared__ float us[256], ts[256];
  const int b = blockIdx.x;
  const int p = blockIdx.y * 256 + threadIdx.x;
  us[threadIdx.x] = u[b * OUTC + threadIdx.x];
  ts[threadIdx.x] = t[b * OUTC + threadIdx.x];
  __syncthreads();
  const float* __restrict__ theta = P + (size_t)b * 512 * 512;
  const float* __restrict__ phi   = theta + 256 * 512;
  float r = 0.f, s = 0.f;
#pragma unroll 8
  for (int k = 0; k < OUTC; ++k) {
    r += us[k] * theta[(size_t)k * 512 + p];
    s += ts[k] * phi[(size_t)k * 512 + p];
  }
  float xe = xe_acc[b * CC + p] * (1.0f / 1024.0f);
  float logit = w4[0] * xe + r + s + b4[0];
  amul[b * CC + p] = 1.0f / (1.0f + expf(-logit));
}

__global__ __launch_bounds__(256) void k5_out(
    const float* __restrict__ x, const float* __restrict__ amul,
    float* __restrict__ out)
{
  int i = blockIdx.x * 256 + threadIdx.x;
  float4 xv = ((const float4*)x)[i];
  float a = amul[i >> 8];
  float4 ov; ov.x = xv.x * a; ov.y = xv.y * a; ov.z = xv.z * a; ov.w = xv.w * a;
  ((float4*)out)[i] = ov;
}

// ===========================================================================
extern "C" void kernel_launch(void* const* d_in, const int* in_sizes, int n_in,
                              void* d_out, int out_size, void* d_ws, size_t ws_size,
                              hipStream_t stream)
{
  (void)in_sizes; (void)n_in; (void)out_size;
  const float* x   = (const float*)d_in[0];
  const float* w1  = (const float*)d_in[1];
  const float* b1  = (const float*)d_in[2];
  const float* g1  = (const float*)d_in[3];
  const float* be1 = (const float*)d_in[4];
  const float* m1  = (const float*)d_in[5];
  const float* v1  = (const float*)d_in[6];
  const float* w2  = (const float*)d_in[7];
  const float* b2  = (const float*)d_in[8];
  const float* g2  = (const float*)d_in[9];
  const float* be2 = (const float*)d_in[10];
  const float* m2  = (const float*)d_in[11];
  const float* v2  = (const float*)d_in[12];
  const float* w3  = (const float*)d_in[13];
  const float* b3  = (const float*)d_in[14];
  const float* g3  = (const float*)d_in[15];
  const float* be3 = (const float*)d_in[16];
  const float* m3  = (const float*)d_in[17];
  const float* v3  = (const float*)d_in[18];
  const float* w4  = (const float*)d_in[19];
  const float* b4  = (const float*)d_in[20];
  float* out = (float*)d_out;

  if (ws_size >= 136970240ull) {
    // ---- split-bf16 MFMA path, 3 dispatches ----
    float* P2     = (float*)d_ws;                       // [32][512][512] fp32
    float* xe_acc = P2 + 8388608;                       // [32][512]
    float* u      = P2 + 8404992;                       // [32][256]
    float* t      = P2 + 8413184;                       // [32][256]
    unsigned short* Xhi  = (unsigned short*)((char*)d_ws + 33685504);
    unsigned short* Xlo  = Xhi + 16777216;
    unsigned short* XThi = Xlo + 16777216;
    unsigned short* Whi  = XThi + 16777216;
    unsigned short* Wlo  = Whi + 524288;
    unsigned short* W3hi = Wlo + 524288;

    prep<<<dim3(16, 8, 33), 256, 0, stream>>>(x, w1, w2, w3, Xhi, Xlo, XThi,
                                              Whi, Wlo, W3hi, xe_acc);
    gemm_fused<<<dim3(2048), 256, 0, stream>>>(Xhi, Xlo, Whi, Wlo, W3hi, XThi,
        b1, g1, be1, m1, v1, b2, g2, be2, m2, v2, b3, g3, be3, m3, v3,
        w4, P2, u, t, xe_acc);
    k4_gate_out<<<dim3(32, 128), 256, 0, stream>>>(P2, u, t, xe_acc, w4, b4, x, out);
  } else {
    // ---- fallback: round-1 fp32 path ----
    float* P      = (float*)d_ws;
    float* xe_acc = P + (size_t)BB * 512 * 512;
    float* u      = xe_acc + BB * CC;
    float* t      = u + BB * OUTC;
    float* amul   = t + BB * OUTC;

    hipMemsetAsync(xe_acc, 0, (size_t)BB * CC * sizeof(float), stream);

    dim3 blk(256);
    k1_theta_phi<<<dim3(8, 8, BB), blk, 0, stream>>>(x, w1, b1, g1, be1, m1, v1,
                                                     w2, b2, g2, be2, m2, v2, P);
    k2_xe<<<dim3(16, 8, BB), blk, 0, stream>>>(x, w3, b3, g3, be3, m3, v3, xe_acc);
    k3_ut<<<dim3(BB, 64), blk, 0, stream>>>(P, w4, u, t);
    k4_gate<<<dim3(BB, 2), blk, 0, stream>>>(P, u, t, xe_acc, w4, b4, amul);
    k5_out<<<dim3((BB * CC * HWW / 4) / 256), blk, 0, stream>>>(x, amul, out);
  }
}

// Round 12
// 263.691 us; speedup vs baseline: 1.0300x; 1.0300x over previous
//
#include <hip/hip_runtime.h>
#include <math.h>

#define BB   32
#define CC   512
#define HWW  1024
#define OUTC 256
#define EPSV 1e-5f

typedef __attribute__((ext_vector_type(8))) short bfrag;
typedef __attribute__((ext_vector_type(4))) float f32x4;
typedef __attribute__((ext_vector_type(4))) unsigned int u32x4;

__device__ inline unsigned short f2bf(float x){
  unsigned int uu = __float_as_uint(x);
  uu += 0x7fff + ((uu >> 16) & 1);      // round-to-nearest-even
  return (unsigned short)(uu >> 16);
}
__device__ inline float bf2f(unsigned short h){
  return __uint_as_float(((unsigned int)h) << 16);
}
// pack two floats -> (bf16 hi pair, bf16 lo-residual pair) words
__device__ inline void packpair(float v0, float v1, unsigned int& hw, unsigned int& lw){
  unsigned short h0 = f2bf(v0), h1 = f2bf(v1);
  unsigned short l0 = f2bf(v0 - bf2f(h0)), l1 = f2bf(v1 - bf2f(h1));
  hw = (unsigned int)h0 | ((unsigned int)h1 << 16);
  lw = (unsigned int)l0 | ((unsigned int)l1 << 16);
}

// ===========================================================================
// MAIN PATH (split-bf16 MFMA, 3 dispatches, fragment-linear layouts)
// ===========================================================================
// Fragment-linear layout: matrix [rows][K] stored as tiles of 16 rows x 32 k.
// Tile (R = row>>4, Kq = k>>5) occupies 512 contiguous shorts; lane
// l = ((k>>3)&3)*16 + (row&15) holds shorts [l*8, l*8+8) (k&7 fastest).
// A wave's MFMA fragment load is ONE coalesced 1KB global_load_dwordx4.
//
// R11 (resubmit after infra failure): R8 config + per-phase s_barrier wave
// alignment. gemm is operand-BW bound: 64KB/phase/CU over ~480cy = 136 B/cy
// vs 56 B/cy L2 ceiling. Wave pairs in a block load IDENTICAL addresses
// (w0/w2 same A, w0/w1 same B) -> aligning waves at each load burst lets the
// duplicate hit L1 (32KB = one phase's unique working set), halving L2
// demand. R10's smaller tile (more B/MFMA) regressed -> traffic is the pacer.

// --- prep: weight-convert + accumulator zeroing (z==32) + x hi/lo + transpose
__global__ __launch_bounds__(256) void prep(
    const float* __restrict__ x,
    const float* __restrict__ w1, const float* __restrict__ w2,
    const float* __restrict__ w3,
    unsigned short* __restrict__ Xhi, unsigned short* __restrict__ Xlo,
    unsigned short* __restrict__ XThi,
    unsigned short* __restrict__ Whi, unsigned short* __restrict__ Wlo,
    unsigned short* __restrict__ W3hi,
    float* __restrict__ accz)          // xe_acc|u|t contiguous, 32768 floats
{
  const int tid = threadIdx.x;
  if (blockIdx.z == 32) {
    int worker = (blockIdx.y * 16 + blockIdx.x) * 256 + tid;  // < 32768
    accz[worker] = 0.f;                 // replaces hipMemsetAsync dispatch
    // W1|W2 -> Whi/Wlo fragment-linear: 1024 tiles x 64 chunks, 2 per worker.
#pragma unroll
    for (int s = 0; s < 2; ++s) {
      int cid  = worker * 2 + s;
      int tile = cid >> 6, l = cid & 63;
      int o = (tile >> 5) * 16 + (l & 15);
      int k = (tile & 31) * 32 + (l >> 4) * 8;
      const float* src = (o < 256) ? (w1 + (size_t)o * 1024 + k)
                                   : (w2 + (size_t)(o - 256) * 1024 + k);
      u32x4 hv, lv;
#pragma unroll
      for (int j = 0; j < 4; ++j) {
        unsigned int hw, lw;
        packpair(src[2 * j], src[2 * j + 1], hw, lw);
        hv[j] = hw; lv[j] = lw;
      }
      size_t base = (size_t)tile * 512 + (size_t)l * 8;
      *(u32x4*)(Whi + base) = hv;
      *(u32x4*)(Wlo + base) = lv;
    }
    // W3 -> W3hi fragment-linear: 512 tiles x 64 chunks, 1 per worker.
    {
      int tile = worker >> 6, l = worker & 63;
      int o = (tile >> 4) * 16 + (l & 15);
      int c = (tile & 15) * 32 + (l >> 4) * 8;
      const float* src = w3 + (size_t)o * 512 + c;
      u32x4 hv;
#pragma unroll
      for (int j = 0; j < 4; ++j) {
        unsigned short h0 = f2bf(src[2 * j]), h1 = f2bf(src[2 * j + 1]);
        hv[j] = (unsigned int)h0 | ((unsigned int)h1 << 16);
      }
      *(u32x4*)(W3hi + (size_t)tile * 512 + (size_t)l * 8) = hv;
    }
    return;
  }
  // ---- x hi/lo + transpose: one 64c x 64p tile per block, all via LDS ----
  __shared__ float T[64][65];
  const int b = blockIdx.z, c0 = blockIdx.y * 64, p0 = blockIdx.x * 64;
  const int tr = tid >> 4, tc4 = (tid & 15) * 4;
  const float* xb = x + (size_t)b * 524288;
#pragma unroll
  for (int r = 0; r < 4; ++r) {
    int cl = tr + r * 16;
    float4 v = *(const float4*)(xb + (size_t)(c0 + cl) * 1024 + p0 + tc4);
    T[cl][tc4 + 0] = v.x; T[cl][tc4 + 1] = v.y;
    T[cl][tc4 + 2] = v.z; T[cl][tc4 + 3] = v.w;
  }
  __syncthreads();
  // Xhi/Xlo: 8 frag tiles (4 cT x 2 pT), 512 chunks, 2 per thread.
#pragma unroll
  for (int s = 0; s < 2; ++s) {
    int cid  = tid + s * 256;
    int tile = cid >> 6, l = cid & 63;
    int tileC = tile >> 1, tileP = tile & 1;
    int cl = tileC * 16 + (l & 15);
    int pl = tileP * 32 + (l >> 4) * 8;
    u32x4 hv, lv;
#pragma unroll
    for (int j = 0; j < 4; ++j) {
      unsigned int hw, lw;
      packpair(T[cl][pl + 2 * j], T[cl][pl + 2 * j + 1], hw, lw);
      hv[j] = hw; lv[j] = lw;
    }
    size_t base = (size_t)b * 524288
                + ((size_t)((c0 + cl) >> 4) * 32 + (size_t)((p0 + pl) >> 5)) * 512
                + (size_t)l * 8;
    *(u32x4*)(Xhi + base) = hv;
    *(u32x4*)(Xlo + base) = lv;
  }
  // XThi: 8 frag tiles (4 pT x 2 cT), 512 chunks, 2 per thread.
#pragma unroll
  for (int s = 0; s < 2; ++s) {
    int cid  = tid + s * 256;
    int tile = cid >> 6, l = cid & 63;
    int tileP = tile >> 1, tileC = tile & 1;
    int pl = tileP * 16 + (l & 15);
    int cl = tileC * 32 + (l >> 4) * 8;
    u32x4 hv;
#pragma unroll
    for (int j = 0; j < 4; ++j) {
      unsigned short h0 = f2bf(T[cl + 2 * j][pl]);
      unsigned short h1 = f2bf(T[cl + 2 * j + 1][pl]);
      hv[j] = (unsigned int)h0 | ((unsigned int)h1 << 16);
    }
    size_t base = (size_t)b * 524288
                + ((size_t)((p0 + pl) >> 4) * 16 + (size_t)((c0 + cl) >> 5)) * 512
                + (size_t)l * 8;
    *(u32x4*)(XThi + base) = hv;
  }
}

// fragment-set helpers (arrays fully unrolled -> registers; rule #20 safe)
__device__ __forceinline__ void g1_load(
    const bfrag* Ah, const bfrag* Al, const bfrag* Bh, const bfrag* Bl,
    int kq, bfrag ah[4], bfrag al[4], bfrag bh[4], bfrag bl[4])
{
#pragma unroll
  for (int j = 0; j < 4; ++j) {
    bh[j] = Bh[(size_t)j * 2048 + kq * 64];
    bl[j] = Bl[(size_t)j * 2048 + kq * 64];
  }
#pragma unroll
  for (int i = 0; i < 4; ++i) {
    ah[i] = Ah[(size_t)i * 2048 + kq * 64];
    al[i] = Al[(size_t)i * 2048 + kq * 64];
  }
  __builtin_amdgcn_sched_barrier(0);   // pin load burst before following MFMAs
}
__device__ __forceinline__ void g1_mfma(
    f32x4 acc[4][4], const bfrag ah[4], const bfrag al[4],
    const bfrag bh[4], const bfrag bl[4])
{
#pragma unroll
  for (int i = 0; i < 4; ++i)
#pragma unroll
    for (int j = 0; j < 4; ++j) {
      acc[i][j] = __builtin_amdgcn_mfma_f32_16x16x32_bf16(ah[i], bh[j], acc[i][j], 0, 0, 0);
      acc[i][j] = __builtin_amdgcn_mfma_f32_16x16x32_bf16(ah[i], bl[j], acc[i][j], 0, 0, 0);
      acc[i][j] = __builtin_amdgcn_mfma_f32_16x16x32_bf16(al[i], bh[j], acc[i][j], 0, 0, 0);
    }
}
__device__ __forceinline__ void g2_load(
    const bfrag* Af, const bfrag* Bf, int kq, bfrag af[4], bfrag bf4[4])
{
#pragma unroll
  for (int i = 0; i < 4; ++i) af[i] = Af[(size_t)i * 1024 + kq * 64];
#pragma unroll
  for (int j = 0; j < 4; ++j) bf4[j] = Bf[(size_t)j * 1024 + kq * 64];
  __builtin_amdgcn_sched_barrier(0);
}
__device__ __forceinline__ void g2_mfma(
    f32x4 acc[4][4], const bfrag af[4], const bfrag bf4[4])
{
#pragma unroll
  for (int i = 0; i < 4; ++i)
#pragma unroll
    for (int j = 0; j < 4; ++j)
      acc[i][j] = __builtin_amdgcn_mfma_f32_16x16x32_bf16(af[i], bf4[j], acc[i][j], 0, 0, 0);
}

// --- gemm_fused: ids [0,512) = g1 (128c x 128oo tiles, split-bf16, K=1024)
//                 ids [512,1536) = g2 (128o x 128p tiles, bf16, K=512)
// LDS-free; fragment-linear operands; register double-buffer;
// per-phase s_barrier aligns waves so duplicate fragment loads (w0/w2 same
// A, w0/w1 same B) dedup in L1.
__global__ __launch_bounds__(256, 2) void gemm_fused(
    const unsigned short* __restrict__ Xhi, const unsigned short* __restrict__ Xlo,
    const unsigned short* __restrict__ Whi, const unsigned short* __restrict__ Wlo,
    const unsigned short* __restrict__ W3hi, const unsigned short* __restrict__ XThi,
    const float* __restrict__ b1p, const float* __restrict__ g1p,
    const float* __restrict__ be1p, const float* __restrict__ m1p, const float* __restrict__ v1p,
    const float* __restrict__ b2p, const float* __restrict__ g2p,
    const float* __restrict__ be2p, const float* __restrict__ m2p, const float* __restrict__ v2p,
    const float* __restrict__ b3p, const float* __restrict__ g3p,
    const float* __restrict__ be3p, const float* __restrict__ m3p, const float* __restrict__ v3p,
    const float* __restrict__ w4,
    float* __restrict__ P2, float* __restrict__ u, float* __restrict__ t,
    float* __restrict__ xe_acc)
{
  const int fid  = blockIdx.x;
  const int tid  = threadIdx.x;
  const int wave = tid >> 6, lane = tid & 63;
  const int fr = lane & 15, fq = lane >> 4;

  if (fid < 512) {
    // ================= g1: P2[b][c][oo] =================
    // XCD decode: the 4 n-tiles of one X-panel (same b,c0) -> same XCD.
    const int xcd = fid & 7;
    const int n0  = ((fid >> 3) & 3) * 128;           // oo tile (128-wide)
    const int bc  = ((fid >> 5) << 3) | xcd;          // 0..127
    const int b   = bc >> 2;
    const int c0  = (bc & 3) * 128;
    const int wm = wave & 1, wn = wave >> 1;          // 64x64 per wave

    const bfrag* Ah = (const bfrag*)Xhi + (size_t)b * 65536
                    + (size_t)((c0 >> 4) + wm * 4) * 2048 + lane;
    const bfrag* Al = (const bfrag*)Xlo + (size_t)b * 65536
                    + (size_t)((c0 >> 4) + wm * 4) * 2048 + lane;
    const bfrag* Bh = (const bfrag*)Whi + (size_t)((n0 >> 4) + wn * 4) * 2048 + lane;
    const bfrag* Bl = (const bfrag*)Wlo + (size_t)((n0 >> 4) + wn * 4) * 2048 + lane;

    f32x4 acc[4][4];
    const f32x4 zz = {0.f, 0.f, 0.f, 0.f};
#pragma unroll
    for (int i = 0; i < 4; ++i)
#pragma unroll
      for (int j = 0; j < 4; ++j) acc[i][j] = zz;

    bfrag ahA[4], alA[4], bhA[4], blA[4];
    bfrag ahB[4], alB[4], bhB[4], blB[4];
    g1_load(Ah, Al, Bh, Bl, 0, ahA, alA, bhA, blA);
    for (int kq = 0; kq < 32; kq += 2) {
      __builtin_amdgcn_s_barrier();      // align waves: duplicate loads -> L1
      g1_load(Ah, Al, Bh, Bl, kq + 1, ahB, alB, bhB, blB);
      g1_mfma(acc, ahA, alA, bhA, blA);
      __builtin_amdgcn_s_barrier();
      if (kq + 2 < 32)
        g1_load(Ah, Al, Bh, Bl, kq + 2, ahA, alA, bhA, blA);
      g1_mfma(acc, ahB, alB, bhB, blB);
    }

    const float *bias, *gg, *bes, *mm, *vv_; int cof;
    if (n0 < 256) { bias = b1p; gg = g1p; bes = be1p; mm = m1p; vv_ = v1p; cof = 0; }
    else          { bias = b2p; gg = g2p; bes = be2p; mm = m2p; vv_ = v2p; cof = 256; }
    const float* wsel = (n0 < 256) ? (w4 + 513) : (w4 + 1);   // theta->t, phi->u
    float* dsel = (n0 < 256) ? (t + b * 256) : (u + b * 256);
    const int cobase = (n0 - cof) + wn * 64;
    float wt[4][4];
#pragma unroll
    for (int i = 0; i < 4; ++i)
#pragma unroll
      for (int r = 0; r < 4; ++r)
        wt[i][r] = wsel[c0 + wm * 64 + i * 16 + fq * 4 + r];

#pragma unroll
    for (int j = 0; j < 4; ++j) {
      int co = n0 + wn * 64 + j * 16 + fr;
      int q = co - cof;
      float s  = gg[q] * rsqrtf(vv_[q] + EPSV);
      float sh = (bias[q] - mm[q]) * s + bes[q];
      float psum = 0.f;
#pragma unroll
      for (int i = 0; i < 4; ++i) {
        int crow = c0 + wm * 64 + i * 16 + fq * 4;
        float* dst = P2 + ((size_t)b * 512 + crow) * 512 + co;
#pragma unroll
        for (int r = 0; r < 4; ++r) {
          float val = fmaxf(acc[i][j][r] * s + sh, 0.f);
          dst[(size_t)r * 512] = val;
          psum += wt[i][r] * val;
        }
      }
      psum += __shfl_xor(psum, 16);
      psum += __shfl_xor(psum, 32);
      if (fq == 0) atomicAdd(&dsel[cobase + j * 16 + fr], psum);
    }
  } else {
    // ================= g2: xe_acc[b][o] =================
    const int h  = fid - 512;
    const int n0 = (h & 7) * 128;                    // p tile
    const int m0 = ((h >> 3) & 3) * 128;             // o tile
    const int b  = h >> 5;
    const int wm = wave & 1, wn = wave >> 1;

    const bfrag* Af = (const bfrag*)W3hi + (size_t)((m0 >> 4) + wm * 4) * 1024 + lane;
    const bfrag* Bf = (const bfrag*)XThi + (size_t)b * 65536
                    + (size_t)((n0 >> 4) + wn * 4) * 1024 + lane;

    f32x4 acc[4][4];
    const f32x4 zz = {0.f, 0.f, 0.f, 0.f};
#pragma unroll
    for (int i = 0; i < 4; ++i)
#pragma unroll
      for (int j = 0; j < 4; ++j) acc[i][j] = zz;

    bfrag afA[4], bfA[4], afB[4], bfB[4];
    g2_load(Af, Bf, 0, afA, bfA);
    for (int kq = 0; kq < 16; kq += 2) {
      __builtin_amdgcn_s_barrier();      // align waves: duplicate loads -> L1
      g2_load(Af, Bf, kq + 1, afB, bfB);
      g2_mfma(acc, afA, bfA);
      __builtin_amdgcn_s_barrier();
      if (kq + 2 < 16)
        g2_load(Af, Bf, kq + 2, afA, bfA);
      g2_mfma(acc, afB, bfB);
    }

#pragma unroll
    for (int i = 0; i < 4; ++i) {
#pragma unroll
      for (int r = 0; r < 4; ++r) {
        int o = m0 + wm * 64 + i * 16 + fq * 4 + r;
        float s  = g3p[o] * rsqrtf(v3p[o] + EPSV);
        float sh = (b3p[o] - m3p[o]) * s + be3p[o];
        float v = fmaxf(acc[i][0][r] * s + sh, 0.f) + fmaxf(acc[i][1][r] * s + sh, 0.f)
                + fmaxf(acc[i][2][r] * s + sh, 0.f) + fmaxf(acc[i][3][r] * s + sh, 0.f);
        v += __shfl_xor(v, 1); v += __shfl_xor(v, 2);
        v += __shfl_xor(v, 4); v += __shfl_xor(v, 8);
        if (fr == 0) atomicAdd(&xe_acc[b * 512 + o], v);
      }
    }
  }
}

// --- k4: logits -> sigmoid -> gate multiply (one wave per (b,p)) ------------
__global__ __launch_bounds__(256) void k4_gate_out(
    const float* __restrict__ P2, const float* __restrict__ u,
    const float* __restrict__ t, const float* __restrict__ xe_acc,
    const float* __restrict__ w4, const float* __restrict__ b4,
    const float* __restrict__ x, float* __restrict__ out)
{
  __shared__ float us[256], ts[256];
  const int b = blockIdx.x;
  us[threadIdx.x] = u[b * 256 + threadIdx.x];
  ts[threadIdx.x] = t[b * 256 + threadIdx.x];
  __syncthreads();
  const int wave = threadIdx.x >> 6, lane = threadIdx.x & 63;
  const int p = blockIdx.y * 4 + wave;
  const float* row = P2 + ((size_t)b * 512 + p) * 512;
  float4 th = *(const float4*)&row[lane * 4];
  float4 ph = *(const float4*)&row[256 + lane * 4];
  int ki = lane * 4;
  float rs = th.x * us[ki] + th.y * us[ki + 1] + th.z * us[ki + 2] + th.w * us[ki + 3]
           + ph.x * ts[ki] + ph.y * ts[ki + 1] + ph.z * ts[ki + 2] + ph.w * ts[ki + 3];
  rs += __shfl_xor(rs, 1);  rs += __shfl_xor(rs, 2);  rs += __shfl_xor(rs, 4);
  rs += __shfl_xor(rs, 8);  rs += __shfl_xor(rs, 16); rs += __shfl_xor(rs, 32);
  float xe = xe_acc[b * 512 + p] * (1.f / 1024.f);
  float logit = w4[0] * xe + rs + b4[0];
  float a = 1.f / (1.f + expf(-logit));
  const float4* xr = (const float4*)(x + ((size_t)b * 512 + p) * 1024);
  float4* orow = (float4*)(out + ((size_t)b * 512 + p) * 1024);
#pragma unroll
  for (int r2 = 0; r2 < 4; ++r2) {
    float4 xv = xr[lane + r2 * 64];
    float4 ov; ov.x = xv.x * a; ov.y = xv.y * a; ov.z = xv.z * a; ov.w = xv.w * a;
    orow[lane + r2 * 64] = ov;
  }
}

// ===========================================================================
// FALLBACK PATH (round-1 fp32, used only if ws_size too small)
// ===========================================================================
__global__ __launch_bounds__(256) void k1_theta_phi(
    const float* __restrict__ x,
    const float* __restrict__ w1, const float* __restrict__ b1,
    const float* __restrict__ g1, const float* __restrict__ be1,
    const float* __restrict__ m1, const float* __restrict__ v1,
    const float* __restrict__ w2, const float* __restrict__ b2,
    const float* __restrict__ g2, const float* __restrict__ be2,
    const float* __restrict__ m2, const float* __restrict__ v2,
    float* __restrict__ P)
{
  __shared__ __align__(16) float Ws[32][68];
  __shared__ __align__(16) float Xs[32][68];
  const int b  = blockIdx.z;
  const int o0 = blockIdx.y * 64;
  const int c0 = blockIdx.x * 64;
  const int tid = threadIdx.x;
  const int tx = tid & 15, ty = tid >> 4;
  const float* __restrict__ Wbase = (o0 < OUTC) ? (w1 + (size_t)o0 * HWW)
                                                : (w2 + (size_t)(o0 - OUTC) * HWW);
  const float* __restrict__ xb = x + (size_t)b * CC * HWW;
  float acc[4][4] = {{0.f}};
  for (int k0 = 0; k0 < HWW; k0 += 32) {
#pragma unroll
    for (int r = 0; r < 2; ++r) {
      int id  = tid + (r << 8);
      int row = id >> 3;
      int cg  = (id & 7) << 2;
      float4 wv = *(const float4*)(Wbase + (size_t)row * HWW + k0 + cg);
      Ws[cg+0][row] = wv.x; Ws[cg+1][row] = wv.y; Ws[cg+2][row] = wv.z; Ws[cg+3][row] = wv.w;
      float4 xv = *(const float4*)(xb + (size_t)(c0 + row) * HWW + k0 + cg);
      Xs[cg+0][row] = xv.x; Xs[cg+1][row] = xv.y; Xs[cg+2][row] = xv.z; Xs[cg+3][row] = xv.w;
    }
    __syncthreads();
#pragma unroll
    for (int k = 0; k < 32; ++k) {
      float4 av = *(const float4*)&Ws[k][ty * 4];
      float4 bv = *(const float4*)&Xs[k][tx * 4];
      acc[0][0] += av.x*bv.x; acc[0][1] += av.x*bv.y; acc[0][2] += av.x*bv.z; acc[0][3] += av.x*bv.w;
      acc[1][0] += av.y*bv.x; acc[1][1] += av.y*bv.y; acc[1][2] += av.y*bv.z; acc[1][3] += av.y*bv.w;
      acc[2][0] += av.z*bv.x; acc[2][1] += av.z*bv.y; acc[2][2] += av.z*bv.z; acc[2][3] += av.z*bv.w;
      acc[3][0] += av.w*bv.x; acc[3][1] += av.w*bv.y; acc[3][2] += av.w*bv.z; acc[3][3] += av.w*bv.w;
    }
    __syncthreads();
  }
  const float *bias, *g, *be, *m, *v; int ob;
  if (o0 < OUTC) { bias = b1; g = g1; be = be1; m = m1; v = v1; ob = o0; }
  else           { bias = b2; g = g2; be = be2; m = m2; v = v2; ob = o0 - OUTC; }
#pragma unroll
  for (int i = 0; i < 4; ++i) {
    int oi = ob + ty * 4 + i;
    float sc = g[oi] * rsqrtf(v[oi] + EPSV);
    float sh = be[oi] - m[oi] * sc;
    float bb = bias[oi];
    float4 ov;
    ov.x = fmaxf((acc[i][0] + bb) * sc + sh, 0.f);
    ov.y = fmaxf((acc[i][1] + bb) * sc + sh, 0.f);
    ov.z = fmaxf((acc[i][2] + bb) * sc + sh, 0.f);
    ov.w = fmaxf((acc[i][3] + bb) * sc + sh, 0.f);
    int oo = o0 + ty * 4 + i;
    *(float4*)(P + ((size_t)b * 512 + oo) * 512 + c0 + tx * 4) = ov;
  }
}

__global__ __launch_bounds__(256) void k2_xe(
    const float* __restrict__ x, const float* __restrict__ w3,
    const float* __restrict__ b3, const float* __restrict__ g3,
    const float* __restrict__ be3, const float* __restrict__ m3,
    const float* __restrict__ v3, float* __restrict__ xe_acc)
{
  __shared__ __align__(16) float As[32][68];
  __shared__ __align__(16) float Bs[32][68];
  const int b  = blockIdx.z;
  const int o0 = blockIdx.y * 64;
  const int p0 = blockIdx.x * 64;
  const int tid = threadIdx.x;
  const int tx = tid & 15, ty = tid >> 4;
  const float* __restrict__ xb = x + (size_t)b * CC * HWW;
  float acc[4][4] = {{0.f}};
  for (int ck = 0; ck < CC; ck += 32) {
#pragma unroll
    for (int r = 0; r < 2; ++r) {
      int id  = tid + (r << 8);
      int row = id >> 3;
      int cg  = (id & 7) << 2;
      float4 wv = *(const float4*)(w3 + (size_t)(o0 + row) * CC + ck + cg);
      As[cg+0][row] = wv.x; As[cg+1][row] = wv.y; As[cg+2][row] = wv.z; As[cg+3][row] = wv.w;
      int brow = id >> 4;
      int pg   = (id & 15) << 2;
      float4 xv = *(const float4*)(xb + (size_t)(ck + brow) * HWW + p0 + pg);
      *(float4*)&Bs[brow][pg] = xv;
    }
    __syncthreads();
#pragma unroll
    for (int k = 0; k < 32; ++k) {
      float4 av = *(const float4*)&As[k][ty * 4];
      float4 bv = *(const float4*)&Bs[k][tx * 4];
      acc[0][0] += av.x*bv.x; acc[0][1] += av.x*bv.y; acc[0][2] += av.x*bv.z; acc[0][3] += av.x*bv.w;
      acc[1][0] += av.y*bv.x; acc[1][1] += av.y*bv.y; acc[1][2] += av.y*bv.z; acc[1][3] += av.y*bv.w;
      acc[2][0] += av.z*bv.x; acc[2][1] += av.z*bv.y; acc[2][2] += av.z*bv.z; acc[2][3] += av.z*bv.w;
      acc[3][0] += av.w*bv.x; acc[3][1] += av.w*bv.y; acc[3][2] += av.w*bv.z; acc[3][3] += av.w*bv.w;
    }
    __syncthreads();
  }
#pragma unroll
  for (int i = 0; i < 4; ++i) {
    int oo = o0 + ty * 4 + i;
    float sc = g3[oo] * rsqrtf(v3[oo] + EPSV);
    float sh = be3[oo] - m3[oo] * sc;
    float bb = b3[oo];
    float ps = fmaxf((acc[i][0] + bb) * sc + sh, 0.f)
             + fmaxf((acc[i][1] + bb) * sc + sh, 0.f)
             + fmaxf((acc[i][2] + bb) * sc + sh, 0.f)
             + fmaxf((acc[i][3] + bb) * sc + sh, 0.f);
    ps += __shfl_xor(ps, 1);
    ps += __shfl_xor(ps, 2);
    ps += __shfl_xor(ps, 4);
    ps += __shfl_xor(ps, 8);
    if (tx == 0) atomicAdd(&xe_acc[b * CC + oo], ps);
  }
}

__global__ __launch_bounds__(256) void k3_ut(
    const float* __restrict__ P, const float* __restrict__ w4,
    float* __restrict__ u, float* __restrict__ t)
{
  const int b = blockIdx.x;
  const int wv = threadIdx.x >> 6, lane = threadIdx.x & 63;
  const int k = blockIdx.y * 4 + wv;
  const float* __restrict__ w4a = w4 + 1;
  const float* __restrict__ w4b = w4 + 1 + CC;
  const float* __restrict__ throw_ = P + ((size_t)b * 512 + k) * 512;
  const float* __restrict__ phrow  = P + ((size_t)b * 512 + 256 + k) * 512;
  float su = 0.f, st = 0.f;
#pragma unroll
  for (int i = lane; i < CC; i += 64) {
    su += w4a[i] * phrow[i];
    st += w4b[i] * throw_[i];
  }
#pragma unroll
  for (int off = 32; off > 0; off >>= 1) {
    su += __shfl_down(su, off);
    st += __shfl_down(st, off);
  }
  if (lane == 0) { u[b * OUTC + k] = su; t[b * OUTC + k] = st; }
}

__global__ __launch_bounds__(256) void k4_gate(
    const float* __restrict__ P, const float* __restrict__ u,
    const float* __restrict__ t, const float* __restrict__ xe_acc,
    const float* __restrict__ w4, const float* __restrict__ b4,
    float* __restrict__ amul)
{
  __shared__ float us[256], ts[256];
  const int b = blockIdx.x;
  const int p = blockIdx.y * 256 + threadIdx.x;
  us[threadIdx.x] = u[b * OUTC + threadIdx.x];
  ts[threadIdx.x] = t[b * OUTC + threadIdx.x];
  __syncthreads();
  const float* __restrict__ theta = P + (size_t)b * 512 * 512;
  const float* __restrict__ phi   = theta + 256 * 512;
  float r = 0.f, s = 0.f;
#pragma unroll 8
  for (int k = 0; k < OUTC; ++k) {
    r += us[k] * theta[(size_t)k * 512 + p];
    s += ts[k] * phi[(size_t)k * 512 + p];
  }
  float xe = xe_acc[b * CC + p] * (1.0f / 1024.0f);
  float logit = w4[0] * xe + r + s + b4[0];
  amul[b * CC + p] = 1.0f / (1.0f + expf(-logit));
}

__global__ __launch_bounds__(256) void k5_out(
    const float* __restrict__ x, const float* __restrict__ amul,
    float* __restrict__ out)
{
  int i = blockIdx.x * 256 + threadIdx.x;
  float4 xv = ((const float4*)x)[i];
  float a = amul[i >> 8];
  float4 ov; ov.x = xv.x * a; ov.y = xv.y * a; ov.z = xv.z * a; ov.w = xv.w * a;
  ((float4*)out)[i] = ov;
}

// ===========================================================================
extern "C" void kernel_launch(void* const* d_in, const int* in_sizes, int n_in,
                              void* d_out, int out_size, void* d_ws, size_t ws_size,
                              hipStream_t stream)
{
  (void)in_sizes; (void)n_in; (void)out_size;
  const float* x   = (const float*)d_in[0];
  const float* w1  = (const float*)d_in[1];
  const float* b1  = (const float*)d_in[2];
  const float* g1  = (const float*)d_in[3];
  const float* be1 = (const float*)d_in[4];
  const float* m1  = (const float*)d_in[5];
  const float* v1  = (const float*)d_in[6];
  const float* w2  = (const float*)d_in[7];
  const float* b2  = (const float*)d_in[8];
  const float* g2  = (const float*)d_in[9];
  const float* be2 = (const float*)d_in[10];
  const float* m2  = (const float*)d_in[11];
  const float* v2  = (const float*)d_in[12];
  const float* w3  = (const float*)d_in[13];
  const float* b3  = (const float*)d_in[14];
  const float* g3  = (const float*)d_in[15];
  const float* be3 = (const float*)d_in[16];
  const float* m3  = (const float*)d_in[17];
  const float* v3  = (const float*)d_in[18];
  const float* w4  = (const float*)d_in[19];
  const float* b4  = (const float*)d_in[20];
  float* out = (float*)d_out;

  if (ws_size >= 136970240ull) {
    // ---- split-bf16 MFMA path, 3 dispatches ----
    float* P2     = (float*)d_ws;                       // [32][512][512] fp32
    float* xe_acc = P2 + 8388608;                       // [32][512]
    float* u      = P2 + 8404992;                       // [32][256]
    float* t      = P2 + 8413184;                       // [32][256]
    unsigned short* Xhi  = (unsigned short*)((char*)d_ws + 33685504);
    unsigned short* Xlo  = Xhi + 16777216;
    unsigned short* XThi = Xlo + 16777216;
    unsigned short* Whi  = XThi + 16777216;
    unsigned short* Wlo  = Whi + 524288;
    unsigned short* W3hi = Wlo + 524288;

    prep<<<dim3(16, 8, 33), 256, 0, stream>>>(x, w1, w2, w3, Xhi, Xlo, XThi,
                                              Whi, Wlo, W3hi, xe_acc);
    gemm_fused<<<dim3(1536), 256, 0, stream>>>(Xhi, Xlo, Whi, Wlo, W3hi, XThi,
        b1, g1, be1, m1, v1, b2, g2, be2, m2, v2, b3, g3, be3, m3, v3,
        w4, P2, u, t, xe_acc);
    k4_gate_out<<<dim3(32, 128), 256, 0, stream>>>(P2, u, t, xe_acc, w4, b4, x, out);
  } else {
    // ---- fallback: round-1 fp32 path ----
    float* P      = (float*)d_ws;
    float* xe_acc = P + (size_t)BB * 512 * 512;
    float* u      = xe_acc + BB * CC;
    float* t      = u + BB * OUTC;
    float* amul   = t + BB * OUTC;

    hipMemsetAsync(xe_acc, 0, (size_t)BB * CC * sizeof(float), stream);

    dim3 blk(256);
    k1_theta_phi<<<dim3(8, 8, BB), blk, 0, stream>>>(x, w1, b1, g1, be1, m1, v1,
                                                     w2, b2, g2, be2, m2, v2, P);
    k2_xe<<<dim3(16, 8, BB), blk, 0, stream>>>(x, w3, b3, g3, be3, m3, v3, xe_acc);
    k3_ut<<<dim3(BB, 64), blk, 0, stream>>>(P, w4, u, t);
    k4_gate<<<dim3(BB, 2), blk, 0, stream>>>(P, u, t, xe_acc, w4, b4, amul);
    k5_out<<<dim3((BB * CC * HWW / 4) / 256), blk, 0, stream>>>(x, amul, out);
  }
}

// Round 13
// 257.436 us; speedup vs baseline: 1.0550x; 1.0243x over previous
//
#include <hip/hip_runtime.h>
#include <math.h>

#define BB   32
#define CC   512
#define HWW  1024
#define OUTC 256
#define EPSV 1e-5f

typedef __attribute__((ext_vector_type(8))) short bfrag;
typedef __attribute__((ext_vector_type(4))) float f32x4;
typedef __attribute__((ext_vector_type(4))) unsigned int u32x4;

__device__ inline unsigned short f2bf(float x){
  unsigned int uu = __float_as_uint(x);
  uu += 0x7fff + ((uu >> 16) & 1);      // round-to-nearest-even
  return (unsigned short)(uu >> 16);
}
__device__ inline float bf2f(unsigned short h){
  return __uint_as_float(((unsigned int)h) << 16);
}
// pack two floats -> (bf16 hi pair, bf16 lo-residual pair) words
__device__ inline void packpair(float v0, float v1, unsigned int& hw, unsigned int& lw){
  unsigned short h0 = f2bf(v0), h1 = f2bf(v1);
  unsigned short l0 = f2bf(v0 - bf2f(h0)), l1 = f2bf(v1 - bf2f(h1));
  hw = (unsigned int)h0 | ((unsigned int)h1 << 16);
  lw = (unsigned int)l0 | ((unsigned int)l1 << 16);
}

#define ASYNC16(g, l) \
  __builtin_amdgcn_global_load_lds((const __attribute__((address_space(1))) unsigned int*)(g), \
                                   (__attribute__((address_space(3))) unsigned int*)(l), 16, 0, 0)
#define WAITV(N) asm volatile("s_waitcnt vmcnt(" #N ")" ::: "memory")

// ===========================================================================
// MAIN PATH (split-bf16 MFMA, 3 dispatches, fragment-linear layouts)
// ===========================================================================
// Fragment-linear layout: matrix [rows][K] stored as tiles of 16 rows x 32 k.
// Tile (R = row>>4, Kq = k>>5) occupies 512 contiguous shorts; lane
// l = ((k>>3)&3)*16 + (row&15) holds shorts [l*8, l*8+8) (k&7 fastest).
//
// R13: LDS-staged gemm. R5-R12 showed the register-direct loop pins at
// MfmaUtil ~33%: wave pairs load every fragment TWICE through the L1 path
// (~128 KB/step/CU vs ~460cy MFMA -> L1-delivery-bound). Fragment-linear
// makes LDS trivial: global_load_lds dest is wave-uniform+lane*16B = exactly
// the layout's lane ownership (no swizzle), ds_read_b128 at lane*16B is
// conflict-free. Stage each tile ONCE per block (halves traffic), feed MFMA
// from LDS (256 B/cy/CU). Dbuf 2x32KB, counted vmcnt (R2/R4-verified
// ledger + R5 fence discipline). Single frag set (~150 VGPR), 2 blocks/CU.

// --- prep: weight-convert + accumulator zeroing (z==32) + x hi/lo + transpose
__global__ __launch_bounds__(256) void prep(
    const float* __restrict__ x,
    const float* __restrict__ w1, const float* __restrict__ w2,
    const float* __restrict__ w3,
    unsigned short* __restrict__ Xhi, unsigned short* __restrict__ Xlo,
    unsigned short* __restrict__ XThi,
    unsigned short* __restrict__ Whi, unsigned short* __restrict__ Wlo,
    unsigned short* __restrict__ W3hi,
    float* __restrict__ accz)          // xe_acc|u|t contiguous, 32768 floats
{
  const int tid = threadIdx.x;
  if (blockIdx.z == 32) {
    int worker = (blockIdx.y * 16 + blockIdx.x) * 256 + tid;  // < 32768
    accz[worker] = 0.f;                 // replaces hipMemsetAsync dispatch
    // W1|W2 -> Whi/Wlo fragment-linear: 1024 tiles x 64 chunks, 2 per worker.
#pragma unroll
    for (int s = 0; s < 2; ++s) {
      int cid  = worker * 2 + s;
      int tile = cid >> 6, l = cid & 63;
      int o = (tile >> 5) * 16 + (l & 15);
      int k = (tile & 31) * 32 + (l >> 4) * 8;
      const float* src = (o < 256) ? (w1 + (size_t)o * 1024 + k)
                                   : (w2 + (size_t)(o - 256) * 1024 + k);
      u32x4 hv, lv;
#pragma unroll
      for (int j = 0; j < 4; ++j) {
        unsigned int hw, lw;
        packpair(src[2 * j], src[2 * j + 1], hw, lw);
        hv[j] = hw; lv[j] = lw;
      }
      size_t base = (size_t)tile * 512 + (size_t)l * 8;
      *(u32x4*)(Whi + base) = hv;
      *(u32x4*)(Wlo + base) = lv;
    }
    // W3 -> W3hi fragment-linear: 512 tiles x 64 chunks, 1 per worker.
    {
      int tile = worker >> 6, l = worker & 63;
      int o = (tile >> 4) * 16 + (l & 15);
      int c = (tile & 15) * 32 + (l >> 4) * 8;
      const float* src = w3 + (size_t)o * 512 + c;
      u32x4 hv;
#pragma unroll
      for (int j = 0; j < 4; ++j) {
        unsigned short h0 = f2bf(src[2 * j]), h1 = f2bf(src[2 * j + 1]);
        hv[j] = (unsigned int)h0 | ((unsigned int)h1 << 16);
      }
      *(u32x4*)(W3hi + (size_t)tile * 512 + (size_t)l * 8) = hv;
    }
    return;
  }
  // ---- x hi/lo + transpose: one 64c x 64p tile per block, all via LDS ----
  __shared__ float T[64][65];
  const int b = blockIdx.z, c0 = blockIdx.y * 64, p0 = blockIdx.x * 64;
  const int tr = tid >> 4, tc4 = (tid & 15) * 4;
  const float* xb = x + (size_t)b * 524288;
#pragma unroll
  for (int r = 0; r < 4; ++r) {
    int cl = tr + r * 16;
    float4 v = *(const float4*)(xb + (size_t)(c0 + cl) * 1024 + p0 + tc4);
    T[cl][tc4 + 0] = v.x; T[cl][tc4 + 1] = v.y;
    T[cl][tc4 + 2] = v.z; T[cl][tc4 + 3] = v.w;
  }
  __syncthreads();
  // Xhi/Xlo: 8 frag tiles (4 cT x 2 pT), 512 chunks, 2 per thread.
#pragma unroll
  for (int s = 0; s < 2; ++s) {
    int cid  = tid + s * 256;
    int tile = cid >> 6, l = cid & 63;
    int tileC = tile >> 1, tileP = tile & 1;
    int cl = tileC * 16 + (l & 15);
    int pl = tileP * 32 + (l >> 4) * 8;
    u32x4 hv, lv;
#pragma unroll
    for (int j = 0; j < 4; ++j) {
      unsigned int hw, lw;
      packpair(T[cl][pl + 2 * j], T[cl][pl + 2 * j + 1], hw, lw);
      hv[j] = hw; lv[j] = lw;
    }
    size_t base = (size_t)b * 524288
                + ((size_t)((c0 + cl) >> 4) * 32 + (size_t)((p0 + pl) >> 5)) * 512
                + (size_t)l * 8;
    *(u32x4*)(Xhi + base) = hv;
    *(u32x4*)(Xlo + base) = lv;
  }
  // XThi: 8 frag tiles (4 pT x 2 cT), 512 chunks, 2 per thread.
#pragma unroll
  for (int s = 0; s < 2; ++s) {
    int cid  = tid + s * 256;
    int tile = cid >> 6, l = cid & 63;
    int tileP = tile >> 1, tileC = tile & 1;
    int pl = tileP * 16 + (l & 15);
    int cl = tileC * 32 + (l >> 4) * 8;
    u32x4 hv;
#pragma unroll
    for (int j = 0; j < 4; ++j) {
      unsigned short h0 = f2bf(T[cl + 2 * j][pl]);
      unsigned short h1 = f2bf(T[cl + 2 * j + 1][pl]);
      hv[j] = (unsigned int)h0 | ((unsigned int)h1 << 16);
    }
    size_t base = (size_t)b * 524288
                + ((size_t)((p0 + pl) >> 4) * 16 + (size_t)((c0 + cl) >> 5)) * 512
                + (size_t)l * 8;
    *(u32x4*)(XThi + base) = hv;
  }
}

// --- gemm_fused: ids [0,512) = g1 (128c x 128oo tiles, split-bf16, K=1024)
//                 ids [512,1536) = g2 (128o x 128p tiles, bf16, K=512)
__global__ __launch_bounds__(256, 2) void gemm_fused(
    const unsigned short* __restrict__ Xhi, const unsigned short* __restrict__ Xlo,
    const unsigned short* __restrict__ Whi, const unsigned short* __restrict__ Wlo,
    const unsigned short* __restrict__ W3hi, const unsigned short* __restrict__ XThi,
    const float* __restrict__ b1p, const float* __restrict__ g1p,
    const float* __restrict__ be1p, const float* __restrict__ m1p, const float* __restrict__ v1p,
    const float* __restrict__ b2p, const float* __restrict__ g2p,
    const float* __restrict__ be2p, const float* __restrict__ m2p, const float* __restrict__ v2p,
    const float* __restrict__ b3p, const float* __restrict__ g3p,
    const float* __restrict__ be3p, const float* __restrict__ m3p, const float* __restrict__ v3p,
    const float* __restrict__ w4,
    float* __restrict__ P2, float* __restrict__ u, float* __restrict__ t,
    float* __restrict__ xe_acc)
{
  __shared__ unsigned short smem[32768];   // 64 KB: g1 2x32KB, g2 2x16KB
  const int fid  = blockIdx.x;
  const int tid  = threadIdx.x;
  const int wave = tid >> 6, lane = tid & 63;
  const int fr = lane & 15, fq = lane >> 4;

  if (fid < 512) {
    // ================= g1: P2[b][c][oo] =================
    // XCD decode: the 4 n-tiles of one X-panel (same b,c0) -> same XCD.
    const int xcd = fid & 7;
    const int n0  = ((fid >> 3) & 3) * 128;           // oo tile (128-wide)
    const int bc  = ((fid >> 5) << 3) | xcd;          // 0..127
    const int b   = bc >> 2;
    const int c0  = (bc & 3) * 128;
    const int wm = wave & 1, wn = wave >> 1;          // 64x64 per wave

    // staging source per wave: w0->Ah(Xhi), w1->Al(Xlo), w2->Bh(Whi), w3->Bl(Wlo)
    // each wave stages 8 tiles (8 KB) per K-step; src per tile is 1KB
    // contiguous at lane*16B -> perfectly coalesced ASYNC16.
    const unsigned short* gsrc;
    int ldst;   // dest offset within buffer (shorts)
    if (wave == 0)      { gsrc = Xhi + (size_t)b * 524288 + (size_t)(c0 >> 4) * 16384; ldst = 0; }
    else if (wave == 1) { gsrc = Xlo + (size_t)b * 524288 + (size_t)(c0 >> 4) * 16384; ldst = 4096; }
    else if (wave == 2) { gsrc = Whi + (size_t)(n0 >> 4) * 16384; ldst = 8192; }
    else                { gsrc = Wlo + (size_t)(n0 >> 4) * 16384; ldst = 12288; }
    gsrc += (size_t)lane * 8;

    f32x4 acc[4][4];
    const f32x4 zz = {0.f, 0.f, 0.f, 0.f};
#pragma unroll
    for (int i = 0; i < 4; ++i)
#pragma unroll
      for (int j = 0; j < 4; ++j) acc[i][j] = zz;

    // prologue: stage K-step 0 into buffer 0
#pragma unroll
    for (int i = 0; i < 8; ++i)
      ASYNC16(gsrc + (size_t)i * 16384, smem + ldst + i * 512);

    int cur = 0;
    for (int kq = 0; kq < 32; ++kq) {
      // fence: ASYNC16s below must not cross the previous bottom s_barrier
      __builtin_amdgcn_sched_barrier(0);
      if (kq + 1 < 32) {
        unsigned short* nb = smem + (cur ^ 1) * 16384 + ldst;
#pragma unroll
        for (int i = 0; i < 8; ++i)
          ASYNC16(gsrc + (size_t)i * 16384 + (kq + 1) * 512, nb + i * 512);
        WAITV(8);    // retire cur's 8 (oldest); next's 8 stay in flight
      } else {
        WAITV(0);
      }
      __builtin_amdgcn_s_barrier();
      __builtin_amdgcn_sched_barrier(0);

      const unsigned short* bufc = smem + cur * 16384;
      bfrag ah[4], al[4], bh[4], bl[4];
#pragma unroll
      for (int i = 0; i < 4; ++i) {
        ah[i] = *(const bfrag*)&bufc[(wm * 4 + i) * 512 + lane * 8];
        al[i] = *(const bfrag*)&bufc[4096 + (wm * 4 + i) * 512 + lane * 8];
      }
#pragma unroll
      for (int j = 0; j < 4; ++j) {
        bh[j] = *(const bfrag*)&bufc[8192 + (wn * 4 + j) * 512 + lane * 8];
        bl[j] = *(const bfrag*)&bufc[12288 + (wn * 4 + j) * 512 + lane * 8];
      }
#pragma unroll
      for (int i = 0; i < 4; ++i)
#pragma unroll
        for (int j = 0; j < 4; ++j) {
          acc[i][j] = __builtin_amdgcn_mfma_f32_16x16x32_bf16(ah[i], bh[j], acc[i][j], 0, 0, 0);
          acc[i][j] = __builtin_amdgcn_mfma_f32_16x16x32_bf16(ah[i], bl[j], acc[i][j], 0, 0, 0);
          acc[i][j] = __builtin_amdgcn_mfma_f32_16x16x32_bf16(al[i], bh[j], acc[i][j], 0, 0, 0);
        }
      __builtin_amdgcn_sched_barrier(0);
      __builtin_amdgcn_s_barrier();   // all waves done reading cur before restage
      cur ^= 1;
    }
    __builtin_amdgcn_sched_barrier(0);

    const float *bias, *gg, *bes, *mm, *vv_; int cof;
    if (n0 < 256) { bias = b1p; gg = g1p; bes = be1p; mm = m1p; vv_ = v1p; cof = 0; }
    else          { bias = b2p; gg = g2p; bes = be2p; mm = m2p; vv_ = v2p; cof = 256; }
    const float* wsel = (n0 < 256) ? (w4 + 513) : (w4 + 1);   // theta->t, phi->u
    float* dsel = (n0 < 256) ? (t + b * 256) : (u + b * 256);
    const int cobase = (n0 - cof) + wn * 64;
    float wt[4][4];
#pragma unroll
    for (int i = 0; i < 4; ++i)
#pragma unroll
      for (int r = 0; r < 4; ++r)
        wt[i][r] = wsel[c0 + wm * 64 + i * 16 + fq * 4 + r];

#pragma unroll
    for (int j = 0; j < 4; ++j) {
      int co = n0 + wn * 64 + j * 16 + fr;
      int q = co - cof;
      float s  = gg[q] * rsqrtf(vv_[q] + EPSV);
      float sh = (bias[q] - mm[q]) * s + bes[q];
      float psum = 0.f;
#pragma unroll
      for (int i = 0; i < 4; ++i) {
        int crow = c0 + wm * 64 + i * 16 + fq * 4;
        float* dst = P2 + ((size_t)b * 512 + crow) * 512 + co;
#pragma unroll
        for (int r = 0; r < 4; ++r) {
          float val = fmaxf(acc[i][j][r] * s + sh, 0.f);
          dst[(size_t)r * 512] = val;
          psum += wt[i][r] * val;
        }
      }
      psum += __shfl_xor(psum, 16);
      psum += __shfl_xor(psum, 32);
      if (fq == 0) atomicAdd(&dsel[cobase + j * 16 + fr], psum);
    }
  } else {
    // ================= g2: xe_acc[b][o] =================
    const int h  = fid - 512;
    const int n0 = (h & 7) * 128;                    // p tile
    const int m0 = ((h >> 3) & 3) * 128;             // o tile
    const int b  = h >> 5;
    const int wm = wave & 1, wn = wave >> 1;

    // staging: w0 -> A tiles 0-3, w1 -> A tiles 4-7, w2 -> B 0-3, w3 -> B 4-7
    // (4 x 1KB ASYNC16 per wave per K-step; buffer 16KB, dbuf at 0 / 8192)
    const unsigned short* gsrc;
    int ldst;
    if (wave < 2) { gsrc = W3hi + (size_t)((m0 >> 4) + wave * 4) * 8192; ldst = wave * 2048; }
    else { gsrc = XThi + (size_t)b * 524288 + (size_t)((n0 >> 4) + (wave - 2) * 4) * 8192;
           ldst = 4096 + (wave - 2) * 2048; }
    gsrc += (size_t)lane * 8;

    f32x4 acc[4][4];
    const f32x4 zz = {0.f, 0.f, 0.f, 0.f};
#pragma unroll
    for (int i = 0; i < 4; ++i)
#pragma unroll
      for (int j = 0; j < 4; ++j) acc[i][j] = zz;

#pragma unroll
    for (int i = 0; i < 4; ++i)
      ASYNC16(gsrc + (size_t)i * 8192, smem + ldst + i * 512);

    int cur = 0;
    for (int kq = 0; kq < 16; ++kq) {
      __builtin_amdgcn_sched_barrier(0);
      if (kq + 1 < 16) {
        unsigned short* nb = smem + (cur ^ 1) * 8192 + ldst;
#pragma unroll
        for (int i = 0; i < 4; ++i)
          ASYNC16(gsrc + (size_t)i * 8192 + (kq + 1) * 512, nb + i * 512);
        WAITV(4);
      } else {
        WAITV(0);
      }
      __builtin_amdgcn_s_barrier();
      __builtin_amdgcn_sched_barrier(0);

      const unsigned short* bufc = smem + cur * 8192;
      bfrag af[4], bf4[4];
#pragma unroll
      for (int i = 0; i < 4; ++i)
        af[i] = *(const bfrag*)&bufc[(wm * 4 + i) * 512 + lane * 8];
#pragma unroll
      for (int j = 0; j < 4; ++j)
        bf4[j] = *(const bfrag*)&bufc[4096 + (wn * 4 + j) * 512 + lane * 8];
#pragma unroll
      for (int i = 0; i < 4; ++i)
#pragma unroll
        for (int j = 0; j < 4; ++j)
          acc[i][j] = __builtin_amdgcn_mfma_f32_16x16x32_bf16(af[i], bf4[j], acc[i][j], 0, 0, 0);
      __builtin_amdgcn_sched_barrier(0);
      __builtin_amdgcn_s_barrier();
      cur ^= 1;
    }
    __builtin_amdgcn_sched_barrier(0);

#pragma unroll
    for (int i = 0; i < 4; ++i) {
#pragma unroll
      for (int r = 0; r < 4; ++r) {
        int o = m0 + wm * 64 + i * 16 + fq * 4 + r;
        float s  = g3p[o] * rsqrtf(v3p[o] + EPSV);
        float sh = (b3p[o] - m3p[o]) * s + be3p[o];
        float v = fmaxf(acc[i][0][r] * s + sh, 0.f) + fmaxf(acc[i][1][r] * s + sh, 0.f)
                + fmaxf(acc[i][2][r] * s + sh, 0.f) + fmaxf(acc[i][3][r] * s + sh, 0.f);
        v += __shfl_xor(v, 1); v += __shfl_xor(v, 2);
        v += __shfl_xor(v, 4); v += __shfl_xor(v, 8);
        if (fr == 0) atomicAdd(&xe_acc[b * 512 + o], v);
      }
    }
  }
}

// --- k4: logits -> sigmoid -> gate multiply (one wave per (b,p)) ------------
__global__ __launch_bounds__(256) void k4_gate_out(
    const float* __restrict__ P2, const float* __restrict__ u,
    const float* __restrict__ t, const float* __restrict__ xe_acc,
    const float* __restrict__ w4, const float* __restrict__ b4,
    const float* __restrict__ x, float* __restrict__ out)
{
  __shared__ float us[256], ts[256];
  const int b = blockIdx.x;
  us[threadIdx.x] = u[b * 256 + threadIdx.x];
  ts[threadIdx.x] = t[b * 256 + threadIdx.x];
  __syncthreads();
  const int wave = threadIdx.x >> 6, lane = threadIdx.x & 63;
  const int p = blockIdx.y * 4 + wave;
  const float* row = P2 + ((size_t)b * 512 + p) * 512;
  float4 th = *(const float4*)&row[lane * 4];
  float4 ph = *(const float4*)&row[256 + lane * 4];
  int ki = lane * 4;
  float rs = th.x * us[ki] + th.y * us[ki + 1] + th.z * us[ki + 2] + th.w * us[ki + 3]
           + ph.x * ts[ki] + ph.y * ts[ki + 1] + ph.z * ts[ki + 2] + ph.w * ts[ki + 3];
  rs += __shfl_xor(rs, 1);  rs += __shfl_xor(rs, 2);  rs += __shfl_xor(rs, 4);
  rs += __shfl_xor(rs, 8);  rs += __shfl_xor(rs, 16); rs += __shfl_xor(rs, 32);
  float xe = xe_acc[b * 512 + p] * (1.f / 1024.f);
  float logit = w4[0] * xe + rs + b4[0];
  float a = 1.f / (1.f + expf(-logit));
  const float4* xr = (const float4*)(x + ((size_t)b * 512 + p) * 1024);
  float4* orow = (float4*)(out + ((size_t)b * 512 + p) * 1024);
#pragma unroll
  for (int r2 = 0; r2 < 4; ++r2) {
    float4 xv = xr[lane + r2 * 64];
    float4 ov; ov.x = xv.x * a; ov.y = xv.y * a; ov.z = xv.z * a; ov.w = xv.w * a;
    orow[lane + r2 * 64] = ov;
  }
}

// ===========================================================================
// FALLBACK PATH (round-1 fp32, used only if ws_size too small)
// ===========================================================================
__global__ __launch_bounds__(256) void k1_theta_phi(
    const float* __restrict__ x,
    const float* __restrict__ w1, const float* __restrict__ b1,
    const float* __restrict__ g1, const float* __restrict__ be1,
    const float* __restrict__ m1, const float* __restrict__ v1,
    const float* __restrict__ w2, const float* __restrict__ b2,
    const float* __restrict__ g2, const float* __restrict__ be2,
    const float* __restrict__ m2, const float* __restrict__ v2,
    float* __restrict__ P)
{
  __shared__ __align__(16) float Ws[32][68];
  __shared__ __align__(16) float Xs[32][68];
  const int b  = blockIdx.z;
  const int o0 = blockIdx.y * 64;
  const int c0 = blockIdx.x * 64;
  const int tid = threadIdx.x;
  const int tx = tid & 15, ty = tid >> 4;
  const float* __restrict__ Wbase = (o0 < OUTC) ? (w1 + (size_t)o0 * HWW)
                                                : (w2 + (size_t)(o0 - OUTC) * HWW);
  const float* __restrict__ xb = x + (size_t)b * CC * HWW;
  float acc[4][4] = {{0.f}};
  for (int k0 = 0; k0 < HWW; k0 += 32) {
#pragma unroll
    for (int r = 0; r < 2; ++r) {
      int id  = tid + (r << 8);
      int row = id >> 3;
      int cg  = (id & 7) << 2;
      float4 wv = *(const float4*)(Wbase + (size_t)row * HWW + k0 + cg);
      Ws[cg+0][row] = wv.x; Ws[cg+1][row] = wv.y; Ws[cg+2][row] = wv.z; Ws[cg+3][row] = wv.w;
      float4 xv = *(const float4*)(xb + (size_t)(c0 + row) * HWW + k0 + cg);
      Xs[cg+0][row] = xv.x; Xs[cg+1][row] = xv.y; Xs[cg+2][row] = xv.z; Xs[cg+3][row] = xv.w;
    }
    __syncthreads();
#pragma unroll
    for (int k = 0; k < 32; ++k) {
      float4 av = *(const float4*)&Ws[k][ty * 4];
      float4 bv = *(const float4*)&Xs[k][tx * 4];
      acc[0][0] += av.x*bv.x; acc[0][1] += av.x*bv.y; acc[0][2] += av.x*bv.z; acc[0][3] += av.x*bv.w;
      acc[1][0] += av.y*bv.x; acc[1][1] += av.y*bv.y; acc[1][2] += av.y*bv.z; acc[1][3] += av.y*bv.w;
      acc[2][0] += av.z*bv.x; acc[2][1] += av.z*bv.y; acc[2][2] += av.z*bv.z; acc[2][3] += av.z*bv.w;
      acc[3][0] += av.w*bv.x; acc[3][1] += av.w*bv.y; acc[3][2] += av.w*bv.z; acc[3][3] += av.w*bv.w;
    }
    __syncthreads();
  }
  const float *bias, *g, *be, *m, *v; int ob;
  if (o0 < OUTC) { bias = b1; g = g1; be = be1; m = m1; v = v1; ob = o0; }
  else           { bias = b2; g = g2; be = be2; m = m2; v = v2; ob = o0 - OUTC; }
#pragma unroll
  for (int i = 0; i < 4; ++i) {
    int oi = ob + ty * 4 + i;
    float sc = g[oi] * rsqrtf(v[oi] + EPSV);
    float sh = be[oi] - m[oi] * sc;
    float bb = bias[oi];
    float4 ov;
    ov.x = fmaxf((acc[i][0] + bb) * sc + sh, 0.f);
    ov.y = fmaxf((acc[i][1] + bb) * sc + sh, 0.f);
    ov.z = fmaxf((acc[i][2] + bb) * sc + sh, 0.f);
    ov.w = fmaxf((acc[i][3] + bb) * sc + sh, 0.f);
    int oo = o0 + ty * 4 + i;
    *(float4*)(P + ((size_t)b * 512 + oo) * 512 + c0 + tx * 4) = ov;
  }
}

__global__ __launch_bounds__(256) void k2_xe(
    const float* __restrict__ x, const float* __restrict__ w3,
    const float* __restrict__ b3, const float* __restrict__ g3,
    const float* __restrict__ be3, const float* __restrict__ m3,
    const float* __restrict__ v3, float* __restrict__ xe_acc)
{
  __shared__ __align__(16) float As[32][68];
  __shared__ __align__(16) float Bs[32][68];
  const int b  = blockIdx.z;
  const int o0 = blockIdx.y * 64;
  const int p0 = blockIdx.x * 64;
  const int tid = threadIdx.x;
  const int tx = tid & 15, ty = tid >> 4;
  const float* __restrict__ xb = x + (size_t)b * CC * HWW;
  float acc[4][4] = {{0.f}};
  for (int ck = 0; ck < CC; ck += 32) {
#pragma unroll
    for (int r = 0; r < 2; ++r) {
      int id  = tid + (r << 8);
      int row = id >> 3;
      int cg  = (id & 7) << 2;
      float4 wv = *(const float4*)(w3 + (size_t)(o0 + row) * CC + ck + cg);
      As[cg+0][row] = wv.x; As[cg+1][row] = wv.y; As[cg+2][row] = wv.z; As[cg+3][row] = wv.w;
      int brow = id >> 4;
      int pg   = (id & 15) << 2;
      float4 xv = *(const float4*)(xb + (size_t)(ck + brow) * HWW + p0 + pg);
      *(float4*)&Bs[brow][pg] = xv;
    }
    __syncthreads();
#pragma unroll
    for (int k = 0; k < 32; ++k) {
      float4 av = *(const float4*)&As[k][ty * 4];
      float4 bv = *(const float4*)&Bs[k][tx * 4];
      acc[0][0] += av.x*bv.x; acc[0][1] += av.x*bv.y; acc[0][2] += av.x*bv.z; acc[0][3] += av.x*bv.w;
      acc[1][0] += av.y*bv.x; acc[1][1] += av.y*bv.y; acc[1][2] += av.y*bv.z; acc[1][3] += av.y*bv.w;
      acc[2][0] += av.z*bv.x; acc[2][1] += av.z*bv.y; acc[2][2] += av.z*bv.z; acc[2][3] += av.z*bv.w;
      acc[3][0] += av.w*bv.x; acc[3][1] += av.w*bv.y; acc[3][2] += av.w*bv.z; acc[3][3] += av.w*bv.w;
    }
    __syncthreads();
  }
#pragma unroll
  for (int i = 0; i < 4; ++i) {
    int oo = o0 + ty * 4 + i;
    float sc = g3[oo] * rsqrtf(v3[oo] + EPSV);
    float sh = be3[oo] - m3[oo] * sc;
    float bb = b3[oo];
    float ps = fmaxf((acc[i][0] + bb) * sc + sh, 0.f)
             + fmaxf((acc[i][1] + bb) * sc + sh, 0.f)
             + fmaxf((acc[i][2] + bb) * sc + sh, 0.f)
             + fmaxf((acc[i][3] + bb) * sc + sh, 0.f);
    ps += __shfl_xor(ps, 1);
    ps += __shfl_xor(ps, 2);
    ps += __shfl_xor(ps, 4);
    ps += __shfl_xor(ps, 8);
    if (tx == 0) atomicAdd(&xe_acc[b * CC + oo], ps);
  }
}

__global__ __launch_bounds__(256) void k3_ut(
    const float* __restrict__ P, const float* __restrict__ w4,
    float* __restrict__ u, float* __restrict__ t)
{
  const int b = blockIdx.x;
  const int wv = threadIdx.x >> 6, lane = threadIdx.x & 63;
  const int k = blockIdx.y * 4 + wv;
  const float* __restrict__ w4a = w4 + 1;
  const float* __restrict__ w4b = w4 + 1 + CC;
  const float* __restrict__ throw_ = P + ((size_t)b * 512 + k) * 512;
  const float* __restrict__ phrow  = P + ((size_t)b * 512 + 256 + k) * 512;
  float su = 0.f, st = 0.f;
#pragma unroll
  for (int i = lane; i < CC; i += 64) {
    su += w4a[i] * phrow[i];
    st += w4b[i] * throw_[i];
  }
#pragma unroll
  for (int off = 32; off > 0; off >>= 1) {
    su += __shfl_down(su, off);
    st += __shfl_down(st, off);
  }
  if (lane == 0) { u[b * OUTC + k] = su; t[b * OUTC + k] = st; }
}

__global__ __launch_bounds__(256) void k4_gate(
    const float* __restrict__ P, const float* __restrict__ u,
    const float* __restrict__ t, const float* __restrict__ xe_acc,
    const float* __restrict__ w4, const float* __restrict__ b4,
    float* __restrict__ amul)
{
  __shared__ float us[256], ts[256];
  const int b = blockIdx.x;
  const int p = blockIdx.y * 256 + threadIdx.x;
  us[threadIdx.x] = u[b * OUTC + threadIdx.x];
  ts[threadIdx.x] = t[b * OUTC + threadIdx.x];
  __syncthreads();
  const float* __restrict__ theta = P + (size_t)b * 512 * 512;
  const float* __restrict__ phi   = theta + 256 * 512;
  float r = 0.f, s = 0.f;
#pragma unroll 8
  for (int k = 0; k < OUTC; ++k) {
    r += us[k] * theta[(size_t)k * 512 + p];
    s += ts[k] * phi[(size_t)k * 512 + p];
  }
  float xe = xe_acc[b * CC + p] * (1.0f / 1024.0f);
  float logit = w4[0] * xe + r + s + b4[0];
  amul[b * CC + p] = 1.0f / (1.0f + expf(-logit));
}

__global__ __launch_bounds__(256) void k5_out(
    const float* __restrict__ x, const float* __restrict__ amul,
    float* __restrict__ out)
{
  int i = blockIdx.x * 256 + threadIdx.x;
  float4 xv = ((const float4*)x)[i];
  float a = amul[i >> 8];
  float4 ov; ov.x = xv.x * a; ov.y = xv.y * a; ov.z = xv.z * a; ov.w = xv.w * a;
  ((float4*)out)[i] = ov;
}

// ===========================================================================
extern "C" void kernel_launch(void* const* d_in, const int* in_sizes, int n_in,
                              void* d_out, int out_size, void* d_ws, size_t ws_size,
                              hipStream_t stream)
{
  (void)in_sizes; (void)n_in; (void)out_size;
  const float* x   = (const float*)d_in[0];
  const float* w1  = (const float*)d_in[1];
  const float* b1  = (const float*)d_in[2];
  const float* g1  = (const float*)d_in[3];
  const float* be1 = (const float*)d_in[4];
  const float* m1  = (const float*)d_in[5];
  const float* v1  = (const float*)d_in[6];
  const float* w2  = (const float*)d_in[7];
  const float* b2  = (const float*)d_in[8];
  const float* g2  = (const float*)d_in[9];
  const float* be2 = (const float*)d_in[10];
  const float* m2  = (const float*)d_in[11];
  const float* v2  = (const float*)d_in[12];
  const float* w3  = (const float*)d_in[13];
  const float* b3  = (const float*)d_in[14];
  const float* g3  = (const float*)d_in[15];
  const float* be3 = (const float*)d_in[16];
  const float* m3  = (const float*)d_in[17];
  const float* v3  = (const float*)d_in[18];
  const float* w4  = (const float*)d_in[19];
  const float* b4  = (const float*)d_in[20];
  float* out = (float*)d_out;

  if (ws_size >= 136970240ull) {
    // ---- split-bf16 MFMA path, 3 dispatches ----
    float* P2     = (float*)d_ws;                       // [32][512][512] fp32
    float* xe_acc = P2 + 8388608;                       // [32][512]
    float* u      = P2 + 8404992;                       // [32][256]
    float* t      = P2 + 8413184;                       // [32][256]
    unsigned short* Xhi  = (unsigned short*)((char*)d_ws + 33685504);
    unsigned short* Xlo  = Xhi + 16777216;
    unsigned short* XThi = Xlo + 16777216;
    unsigned short* Whi  = XThi + 16777216;
    unsigned short* Wlo  = Whi + 524288;
    unsigned short* W3hi = Wlo + 524288;

    prep<<<dim3(16, 8, 33), 256, 0, stream>>>(x, w1, w2, w3, Xhi, Xlo, XThi,
                                              Whi, Wlo, W3hi, xe_acc);
    gemm_fused<<<dim3(1536), 256, 0, stream>>>(Xhi, Xlo, Whi, Wlo, W3hi, XThi,
        b1, g1, be1, m1, v1, b2, g2, be2, m2, v2, b3, g3, be3, m3, v3,
        w4, P2, u, t, xe_acc);
    k4_gate_out<<<dim3(32, 128), 256, 0, stream>>>(P2, u, t, xe_acc, w4, b4, x, out);
  } else {
    // ---- fallback: round-1 fp32 path ----
    float* P      = (float*)d_ws;
    float* xe_acc = P + (size_t)BB * 512 * 512;
    float* u      = xe_acc + BB * CC;
    float* t      = u + BB * OUTC;
    float* amul   = t + BB * OUTC;

    hipMemsetAsync(xe_acc, 0, (size_t)BB * CC * sizeof(float), stream);

    dim3 blk(256);
    k1_theta_phi<<<dim3(8, 8, BB), blk, 0, stream>>>(x, w1, b1, g1, be1, m1, v1,
                                                     w2, b2, g2, be2, m2, v2, P);
    k2_xe<<<dim3(16, 8, BB), blk, 0, stream>>>(x, w3, b3, g3, be3, m3, v3, xe_acc);
    k3_ut<<<dim3(BB, 64), blk, 0, stream>>>(P, w4, u, t);
    k4_gate<<<dim3(BB, 2), blk, 0, stream>>>(P, u, t, xe_acc, w4, b4, amul);
    k5_out<<<dim3((BB * CC * HWW / 4) / 256), blk, 0, stream>>>(x, amul, out);
  }
}